// Round 2
// baseline (9418.152 us; speedup 1.0000x reference)
//
#include <hip/hip_runtime.h>
#include <math.h>

// ---------------- problem sizes ----------------
#define NB 8
#define NN 56
#define POS 3136             // 56*56
#define ROWS 25088           // 8*3136
#define GR 111               // 2N-1
#define GROWS 12321          // 111*111
#define FREQ 16640           // per-channel spectrum floats: re 128x65 | im 128x65

// ---------------- workspace layout (float offsets), total 45.2 MB ----------------
#define OFF_RTC   0u          // 111x130
#define OFF_MV    14432u      // 256x112
#define OFF_MG    43104u      // 256x222
#define OFF_M2    99936u      // 112x256
#define OFF_RT2   128608u     // 130x56
#define OFF_NINV  135888u     // 25088
#define OFF_SINV  160976u     // 12321
#define OFF_TB    173312u     // 12321x512 rpe hidden (persistent through head loop)
#define OFF_POOL  6481664u    // per-head pool, 4,816,896 floats
// pool internal (relative to OFF_POOL):
//   g_row : +0         (1,577,088)   steps 1-2
//   g_cm  : +1,577,088 (1,577,088)   steps 2-3
//   vcm   : +0         (3,211,264)   steps 4-7 (in-place vfft -> y_cm)
//   Ghat  : +3,211,264 (2,129,920)   steps 3-5
//   u bf16: +3,211,264 (1,605,632 fl = 3,211,264 bf16) steps 6-7 (aliases dead Ghat)
#define POOL_GCM  1577088u
#define POOL_GHAT 3211264u
#define POOL_U    3211264u
#define WS_FLOATS 11298560u   // = OFF_POOL + 4,816,896  -> 45,194,240 bytes

// tA (rpe ping, 12321x512 = 6,308,352 fl) lives in d_out (12,845,056 fl), dead
// before head 0's output-projection write.

// ---------------- bf16 helpers ----------------
__device__ inline float bf2f(unsigned short b) {
    union { unsigned u; float f; } v; v.u = ((unsigned)b) << 16; return v.f;
}
__device__ inline unsigned short f2bf(float f) {
    union { float f; unsigned u; } v; v.f = f;
    unsigned r = v.u + 0x7FFF + ((v.u >> 16) & 1);
    return (unsigned short)(r >> 16);
}

// =====================================================================
// diagnostic: if workspace insufficient, encode its size into out[0]
// =====================================================================
__global__ void probe_k(float* out, float code) { out[0] = code; }

// =====================================================================
// constants: DFT cos/sin matrices. angle reduced exactly: (a*b) mod 128
// =====================================================================
__global__ void consts_k(float* RTc, float* Mv, float* Mg, float* M2c, float* RT2c) {
    int idx = blockIdx.x * 256 + threadIdx.x;
    const float STEP = 0.049087385212340526f; // 2*pi/128
    if (idx < 14430) { // RTc[q*130+col]: forward row DFT (along q), rfft cols
        int q = idx / 130, col = idx % 130;
        int a = (col < 65) ? col : col - 65;
        float th = (float)((a * q) & 127) * STEP;
        RTc[idx] = (col < 65) ? cosf(th) : -sinf(th);
        return;
    }
    idx -= 14430;
    if (idx < 28672) { // Mv[r*112+s]: forward col DFT for v (p 0..55)
        int r = idx / 112, s = idx % 112;
        int kp = (r < 128) ? r : r - 128;
        int sp = (s < 56) ? s : s - 56;
        float th = (float)((kp * sp) & 127) * STEP;
        float cv = cosf(th), sv = sinf(th);
        Mv[idx] = (r < 128) ? ((s < 56) ? cv : sv) : ((s < 56) ? -sv : cv);
        return;
    }
    idx -= 28672;
    if (idx < 56832) { // Mg[r*222+s]: forward col DFT for g (i 0..110)
        int r = idx / 222, s = idx % 222;
        int kp = (r < 128) ? r : r - 128;
        int sp = (s < 111) ? s : s - 111;
        float th = (float)((kp * sp) & 127) * STEP;
        float cv = cosf(th), sv = sinf(th);
        Mg[idx] = (r < 128) ? ((s < 111) ? cv : sv) : ((s < 111) ? -sv : cv);
        return;
    }
    idx -= 56832;
    if (idx < 28672) { // M2c[r*256+s]: inverse col DFT at rows a=p+55
        int r = idx / 256, s = idx % 256;
        int a = (r < 56) ? (r + 55) : (r - 1); // r>=56: Q_im row, a = (r-56)+55
        int kp = (s < 128) ? s : s - 128;
        float th = (float)((kp * a) & 127) * STEP;
        float cv = cosf(th), sv = sinf(th);
        M2c[idx] = (r < 56) ? ((s < 128) ? cv : -sv) : ((s < 128) ? sv : cv);
        return;
    }
    idx -= 28672;
    if (idx < 7280) { // RT2c[s*56+b]: inverse row DFT cols b'=b+55, w/L^2 folded
        int s = idx / 56, b = idx % 56;
        int kq = (s < 65) ? s : s - 65;
        float w = (kq == 0 || kq == 64) ? 1.f : 2.f;
        float th = (float)((kq * (b + 55)) & 127) * STEP;
        float val = (s < 65) ? cosf(th) : -sinf(th);
        RT2c[idx] = val * w * (1.f / 16384.f);
    }
}

// =====================================================================
// row L2 norms -> inverse simple-rms scale  1/(||x||*d^-0.5 + eps), D=512
// =====================================================================
__global__ void norms_k(const float* __restrict__ X, float* __restrict__ out, int rows) {
    int row = blockIdx.x * 4 + (threadIdx.x >> 6);
    int lane = threadIdx.x & 63;
    if (row >= rows) return;
    const float* p = X + (size_t)row * 512;
    float s = 0.f;
    #pragma unroll
    for (int i = 0; i < 8; ++i) { float v = p[lane + 64 * i]; s += v * v; }
    #pragma unroll
    for (int o = 32; o > 0; o >>= 1) s += __shfl_down(s, o, 64);
    if (lane == 0) out[row] = 1.f / (sqrtf(s) * 0.04419417382415922f + 1e-8f);
}

// =====================================================================
// t0 = coords @ rpe_in_w.T + rpe_in_b    (12321 x 512)
// =====================================================================
__global__ void t0_k(const float* __restrict__ w, const float* __restrict__ b, float* __restrict__ out) {
    int idx = blockIdx.x * 256 + threadIdx.x;
    if (idx >= GROWS * 512) return;
    int r = idx >> 9, c = idx & 511;
    int i = r / 111, j = r % 111;
    float dp = (float)(i - 55), dq = (float)(j - 55);
    out[idx] = dp * w[c * 2] + dq * w[c * 2 + 1] + b[c];
}

// =====================================================================
// generic fp32 GEMM: C[M,N] = act( (scale*f(A))[M,K] @ B[N,K]^T + bias )
//   f(a) = in_relu ? relu(a) : a ; scale = in_scale[row] (or 1)
//   act_silu: 0=none 1=silu
//   out_mode: 0 = row-major fp32 ; 1 = channel-major fp32 (v path, N==128,
//             dst[((r/3136)*128 + c)*3136 + r%3136]) ; 2 = row-major bf16
// 64x64 tile, 256 threads, 4x4 accum/thread, K-chunks of 16
// =====================================================================
__global__ __launch_bounds__(256) void gemm_k(
    const float* __restrict__ A, const float* __restrict__ B,
    void* __restrict__ C, const float* __restrict__ bias,
    const float* __restrict__ in_scale, int in_relu, int act_silu,
    int out_mode, int M, int N, int K)
{
    __shared__ float As[16][64];
    __shared__ float Bs[16][64];
    const int tid = threadIdx.x;
    const int tx = tid & 15, ty = tid >> 4;
    const int row0 = blockIdx.y * 64, col0 = blockIdx.x * 64;
    const int lr = tid >> 2, lk = (tid & 3) << 2;
    float acc[4][4] = {};
    const int ar = row0 + lr;
    float s = 1.0f;
    if (in_scale && ar < M) s = in_scale[ar];
    const float* Arow = (ar < M) ? (A + (size_t)ar * K) : nullptr;
    const float* Brow = B + (size_t)(col0 + lr) * K;
    for (int k0 = 0; k0 < K; k0 += 16) {
        float4 av = make_float4(0.f, 0.f, 0.f, 0.f);
        if (Arow) av = *(const float4*)(Arow + k0 + lk);
        if (in_relu) {
            av.x = fmaxf(av.x, 0.f); av.y = fmaxf(av.y, 0.f);
            av.z = fmaxf(av.z, 0.f); av.w = fmaxf(av.w, 0.f);
        }
        As[lk + 0][lr] = av.x * s; As[lk + 1][lr] = av.y * s;
        As[lk + 2][lr] = av.z * s; As[lk + 3][lr] = av.w * s;
        float4 bv = *(const float4*)(Brow + k0 + lk);
        Bs[lk + 0][lr] = bv.x; Bs[lk + 1][lr] = bv.y;
        Bs[lk + 2][lr] = bv.z; Bs[lk + 3][lr] = bv.w;
        __syncthreads();
        #pragma unroll
        for (int kk = 0; kk < 16; ++kk) {
            const float4 a4 = *(const float4*)&As[kk][ty << 2];
            const float4 b4 = *(const float4*)&Bs[kk][tx << 2];
            float avv[4] = {a4.x, a4.y, a4.z, a4.w};
            float bvv[4] = {b4.x, b4.y, b4.z, b4.w};
            #pragma unroll
            for (int i = 0; i < 4; ++i)
                #pragma unroll
                for (int j = 0; j < 4; ++j)
                    acc[i][j] = fmaf(avv[i], bvv[j], acc[i][j]);
        }
        __syncthreads();
    }
    #pragma unroll
    for (int i = 0; i < 4; ++i) {
        int r = row0 + (ty << 2) + i;
        if (r >= M) break;
        #pragma unroll
        for (int j = 0; j < 4; ++j) {
            int c = col0 + (tx << 2) + j;
            float v = acc[i][j] + bias[c];
            if (act_silu) v = v / (1.f + expf(-v));
            if (out_mode == 0) {
                ((float*)C)[(size_t)r * N + c] = v;
            } else if (out_mode == 1) {
                int b = r / POS, pos = r - b * POS;
                ((float*)C)[((size_t)(b * 128 + c)) * POS + pos] = v;
            } else {
                ((unsigned short*)C)[(size_t)r * N + c] = f2bf(v);
            }
        }
    }
}

// =====================================================================
// transpose: src [nrows x 128] row-major -> dst [128 x nrows]
// =====================================================================
__global__ void transpose128_k(const float* __restrict__ src, float* __restrict__ dst, int nrows) {
    __shared__ float tile[32][33];
    int r0 = blockIdx.x * 32, c0 = blockIdx.y * 32;
    int tx = threadIdx.x, ty = threadIdx.y;
    #pragma unroll
    for (int i = 0; i < 32; i += 8) {
        int r = r0 + ty + i;
        if (r < nrows) tile[ty + i][tx] = src[(size_t)r * 128 + c0 + tx];
    }
    __syncthreads();
    int r = r0 + tx;
    if (r < nrows) {
        #pragma unroll
        for (int i = 0; i < 32; i += 8)
            dst[(size_t)(c0 + ty + i) * nrows + r] = tile[tx][ty + i];
    }
}

// =====================================================================
// g spectrum (one head): block (d, kq-chunk): Ghat_d = DFT2_128(pad(g_d 111x111))
// Ghat layout per d: [re 128x65 | im 128x65]
// =====================================================================
__global__ __launch_bounds__(512) void gfft_k(
    const float* __restrict__ gcm, const float* __restrict__ RTc,
    const float* __restrict__ Mg, float* __restrict__ Ghat)
{
    __shared__ float Gs[GROWS];      // 12321
    __shared__ float Tg[222 * 17];
    int tid = threadIdx.x, d = blockIdx.x, kq0 = blockIdx.y * 17;
    int C = min(17, 65 - kq0), C2 = 2 * C;
    const float* src = gcm + (size_t)d * GROWS;
    for (int i = tid; i < GROWS; i += 512) Gs[i] = src[i];
    float* gout = Ghat + (size_t)d * FREQ;
    __syncthreads();
    for (int o = tid; o < 111 * C2; o += 512) {   // row DFT
        int p = o / C2, cc = o % C2;
        int col = (cc < C) ? (kq0 + cc) : (65 + kq0 + (cc - C));
        const float* gp = Gs + p * 111;
        const float* rp = RTc + col;
        float acc = 0.f;
        #pragma unroll 8
        for (int q = 0; q < 111; ++q) acc = fmaf(gp[q], rp[q * 130], acc);
        Tg[p * C2 + cc] = acc;
    }
    __syncthreads();
    for (int o = tid; o < 128 * C; o += 512) {    // col DFT, write global
        int r = o / C, c = o % C;
        const float* m1 = Mg + (size_t)r * 222;
        const float* m2 = Mg + (size_t)(r + 128) * 222;
        float a1 = 0.f, a2 = 0.f;
        #pragma unroll 8
        for (int ss = 0; ss < 111; ++ss) {
            float tre = Tg[ss * C2 + c];
            a1 = fmaf(m1[ss], tre, a1); a2 = fmaf(m2[ss], tre, a2);
        }
        #pragma unroll 8
        for (int ss = 0; ss < 111; ++ss) {
            float tim = Tg[ss * C2 + C + c];
            a1 = fmaf(m1[111 + ss], tim, a1); a2 = fmaf(m2[111 + ss], tim, a2);
        }
        gout[r * 65 + kq0 + c] = a1;
        gout[8320 + r * 65 + kq0 + c] = a2;
    }
}

// =====================================================================
// v conv (one head, in-place): block = (d, b): y = icirc128(DFT2(pad(v)) * Ghat_d)
// rows 55..110, cols 55..110 of the 128x128 inverse = the 56x56 output
// =====================================================================
__global__ __launch_bounds__(512) void vfft_k(
    float* __restrict__ vcm, const float* __restrict__ Ghat,
    const float* __restrict__ RTc, const float* __restrict__ Mv,
    const float* __restrict__ M2c, const float* __restrict__ RT2c)
{
    __shared__ float Vs[POS];
    __shared__ float Ys[POS];
    __shared__ float Tq[112 * 17];
    __shared__ float Vh[256 * 17];
    int tid = threadIdx.x, bid = blockIdx.x;
    int d = bid >> 3, b = bid & 7;
    float* chan = vcm + (size_t)(b * 128 + d) * POS;
    for (int i = tid; i < POS; i += 512) { Vs[i] = chan[i]; Ys[i] = 0.f; }
    const float* gre = Ghat + (size_t)d * FREQ;
    for (int kq0 = 0; kq0 < 65; kq0 += 17) {
        int C = min(17, 65 - kq0), C2 = 2 * C;
        __syncthreads();
        // S1: forward row DFT -> Tq[p][cc]
        for (int o = tid; o < 56 * C2; o += 512) {
            int p = o / C2, cc = o % C2;
            int col = (cc < C) ? (kq0 + cc) : (65 + kq0 + (cc - C));
            const float* vp = Vs + p * 56;
            const float* rp = RTc + col;
            float acc = 0.f;
            #pragma unroll 8
            for (int q = 0; q < 56; ++q) acc = fmaf(vp[q], rp[q * 130], acc);
            Tq[p * C2 + cc] = acc;
        }
        __syncthreads();
        // S2: forward col DFT -> Vh[256][C]
        for (int o = tid; o < 128 * C; o += 512) {
            int r = o / C, c = o % C;
            const float* m1 = Mv + (size_t)r * 112;
            const float* m2 = Mv + (size_t)(r + 128) * 112;
            float a1 = 0.f, a2 = 0.f;
            #pragma unroll 8
            for (int ss = 0; ss < 56; ++ss) {
                float tre = Tq[ss * C2 + c];
                a1 = fmaf(m1[ss], tre, a1); a2 = fmaf(m2[ss], tre, a2);
            }
            #pragma unroll 8
            for (int ss = 0; ss < 56; ++ss) {
                float tim = Tq[ss * C2 + C + c];
                a1 = fmaf(m1[56 + ss], tim, a1); a2 = fmaf(m2[56 + ss], tim, a2);
            }
            Vh[r * C + c] = a1;
            Vh[(r + 128) * C + c] = a2;
        }
        __syncthreads();
        // S3: pointwise complex multiply with Ghat
        for (int o = tid; o < 128 * C; o += 512) {
            int kp = o / C, c = o % C;
            int gi = kp * 65 + kq0 + c;
            float vr = Vh[kp * C + c], vi = Vh[(128 + kp) * C + c];
            float gr = gre[gi], gm = gre[8320 + gi];
            Vh[kp * C + c] = vr * gr - vi * gm;
            Vh[(128 + kp) * C + c] = vr * gm + vi * gr;
        }
        __syncthreads();
        // S4: inverse col DFT (rows a=p+55) -> Q[112][C] (alias Tq)
        for (int o = tid; o < 56 * C; o += 512) {
            int r = o / C, c = o % C;
            const float* m1 = M2c + (size_t)r * 256;
            const float* m2 = M2c + (size_t)(r + 56) * 256;
            float a1 = 0.f, a2 = 0.f;
            #pragma unroll 8
            for (int ss = 0; ss < 256; ++ss) {
                float pv = Vh[ss * C + c];
                a1 = fmaf(m1[ss], pv, a1); a2 = fmaf(m2[ss], pv, a2);
            }
            Tq[r * C + c] = a1;
            Tq[(r + 56) * C + c] = a2;
        }
        __syncthreads();
        // S5: inverse row DFT (cols b'=q+55), accumulate into Ys
        for (int o = tid; o < POS; o += 512) {
            int p = o / 56, bq = o % 56;
            float acc = Ys[o];
            const float* q1 = Tq + p * C;
            const float* q2 = Tq + (56 + p) * C;
            #pragma unroll 4
            for (int c = 0; c < C; ++c) {
                int kq = kq0 + c;
                acc = fmaf(q1[c], RT2c[kq * 56 + bq], acc);
                acc = fmaf(q2[c], RT2c[(65 + kq) * 56 + bq], acc);
            }
            Ys[o] = acc;
        }
    }
    __syncthreads();
    for (int i = tid; i < POS; i += 512) chan[i] = Ys[i];
}

// =====================================================================
// final projection, one head, split-K accumulate:
//   out[r, n] (+)= sum_k (u_bf16[r,k] * ycm[(b*128+k)*POS+pos]) * Wo[n, h*128+k]
//   first: += b_o[n] + x[r, n]   else: += out[r, n]
// =====================================================================
__global__ __launch_bounds__(256) void gemmW_k(
    const unsigned short* __restrict__ u, const float* __restrict__ ycm,
    const float* __restrict__ Wo, const float* __restrict__ bo,
    const float* __restrict__ x, float* __restrict__ out, int h, int first)
{
    __shared__ float As[16][64];
    __shared__ float Bs[16][64];
    const int tid = threadIdx.x;
    const int tx = tid & 15, ty = tid >> 4;
    const int row0 = blockIdx.y * 64, col0 = blockIdx.x * 64;
    const int lr = tid >> 2, lk = (tid & 3) << 2;
    const int ar = row0 + lr;                 // < 25088 always
    const int b = ar / POS, pos = ar - b * POS;
    const unsigned short* urow = u + (size_t)ar * 128;
    const float* ybase = ycm + (size_t)(b * 128) * POS + pos;
    const float* Brow = Wo + (size_t)(col0 + lr) * 1024 + h * 128;
    float acc[4][4] = {};
    for (int k0 = 0; k0 < 128; k0 += 16) {
        ushort4 uv = *(const ushort4*)(urow + k0 + lk);
        float y0 = ybase[(size_t)(k0 + lk + 0) * POS];
        float y1 = ybase[(size_t)(k0 + lk + 1) * POS];
        float y2 = ybase[(size_t)(k0 + lk + 2) * POS];
        float y3 = ybase[(size_t)(k0 + lk + 3) * POS];
        As[lk + 0][lr] = bf2f(uv.x) * y0;
        As[lk + 1][lr] = bf2f(uv.y) * y1;
        As[lk + 2][lr] = bf2f(uv.z) * y2;
        As[lk + 3][lr] = bf2f(uv.w) * y3;
        float4 bv = *(const float4*)(Brow + k0 + lk);
        Bs[lk + 0][lr] = bv.x; Bs[lk + 1][lr] = bv.y;
        Bs[lk + 2][lr] = bv.z; Bs[lk + 3][lr] = bv.w;
        __syncthreads();
        #pragma unroll
        for (int kk = 0; kk < 16; ++kk) {
            const float4 a4 = *(const float4*)&As[kk][ty << 2];
            const float4 b4 = *(const float4*)&Bs[kk][tx << 2];
            float avv[4] = {a4.x, a4.y, a4.z, a4.w};
            float bvv[4] = {b4.x, b4.y, b4.z, b4.w};
            #pragma unroll
            for (int i = 0; i < 4; ++i)
                #pragma unroll
                for (int j = 0; j < 4; ++j)
                    acc[i][j] = fmaf(avv[i], bvv[j], acc[i][j]);
        }
        __syncthreads();
    }
    #pragma unroll
    for (int i = 0; i < 4; ++i) {
        int r = row0 + (ty << 2) + i;
        #pragma unroll
        for (int j = 0; j < 4; ++j) {
            int c = col0 + (tx << 2) + j;
            size_t oi = (size_t)r * 512 + c;
            float v = acc[i][j];
            v += first ? (bo[c] + x[oi]) : out[oi];
            out[oi] = v;
        }
    }
}

// =====================================================================
extern "C" void kernel_launch(void* const* d_in, const int* in_sizes, int n_in,
                              void* d_out, int out_size, void* d_ws, size_t ws_size,
                              hipStream_t stream) {
    (void)in_sizes; (void)n_in; (void)out_size;
    const float* x         = (const float*)d_in[0];
    const float* W_u       = (const float*)d_in[1];
    const float* b_u       = (const float*)d_in[2];
    const float* W_v       = (const float*)d_in[3];
    const float* b_v       = (const float*)d_in[4];
    const float* W_o       = (const float*)d_in[5];
    const float* b_o       = (const float*)d_in[6];
    const float* rpe_in_w  = (const float*)d_in[7];
    const float* rpe_in_b  = (const float*)d_in[8];
    const float* rpe_h_w   = (const float*)d_in[9];
    const float* rpe_h_b   = (const float*)d_in[10];
    const float* rpe_out_w = (const float*)d_in[11];
    const float* rpe_out_b = (const float*)d_in[12];
    float* out = (float*)d_out;

    if (ws_size < (size_t)WS_FLOATS * 4) {
        // diagnostic: absmax will read ~= 1000 + ws_MB
        probe_k<<<1, 1, 0, stream>>>(out, 1000.0f + (float)((double)ws_size * 1e-6));
        return;
    }
    float* ws    = (float*)d_ws;
    float* RTc   = ws + OFF_RTC;
    float* Mv    = ws + OFF_MV;
    float* Mg    = ws + OFF_MG;
    float* M2c   = ws + OFF_M2;
    float* RT2c  = ws + OFF_RT2;
    float* ninv  = ws + OFF_NINV;
    float* sinv  = ws + OFF_SINV;
    float* tB    = ws + OFF_TB;
    float* pool  = ws + OFF_POOL;
    float* g_row = pool;
    float* g_cm  = pool + POOL_GCM;
    float* vcm   = pool;
    float* Ghat  = pool + POOL_GHAT;
    unsigned short* uB = (unsigned short*)(pool + POOL_U);
    float* tA    = out;   // rpe ping lives in d_out; dead before head 0 writes out

    consts_k<<<531, 256, 0, stream>>>(RTc, Mv, Mg, M2c, RT2c);

    // ---- RPE MLP hidden layers (head-independent) ----
    t0_k<<<24642, 256, 0, stream>>>(rpe_in_w, rpe_in_b, tA);
    norms_k<<<3081, 256, 0, stream>>>(tA, sinv, GROWS);
    gemm_k<<<dim3(8, 193), 256, 0, stream>>>(tA, rpe_h_w,          tB, rpe_h_b,        sinv, 1, 0, 0, GROWS, 512, 512);
    norms_k<<<3081, 256, 0, stream>>>(tB, sinv, GROWS);
    gemm_k<<<dim3(8, 193), 256, 0, stream>>>(tB, rpe_h_w + 262144, tA, rpe_h_b + 512,  sinv, 1, 0, 0, GROWS, 512, 512);
    norms_k<<<3081, 256, 0, stream>>>(tA, sinv, GROWS);
    gemm_k<<<dim3(8, 193), 256, 0, stream>>>(tA, rpe_h_w + 524288, tB, rpe_h_b + 1024, sinv, 1, 0, 0, GROWS, 512, 512);
    norms_k<<<3081, 256, 0, stream>>>(tB, sinv, GROWS);

    // ---- x norms (once) ----
    norms_k<<<6272, 256, 0, stream>>>(x, ninv, ROWS);

    // ---- per-head main path, split-K accumulation into out ----
    for (int h = 0; h < 8; ++h) {
        const size_t wo = (size_t)h * 128 * 512;   // offset into [1024,512] weights
        gemm_k<<<dim3(2, 193), 256, 0, stream>>>(tB, rpe_out_w + wo, g_row, rpe_out_b + h * 128, sinv, 1, 0, 0, GROWS, 128, 512);
        transpose128_k<<<dim3(386, 4), dim3(32, 8), 0, stream>>>(g_row, g_cm, GROWS);
        gfft_k<<<dim3(128, 4), 512, 0, stream>>>(g_cm, RTc, Mg, Ghat);
        gemm_k<<<dim3(2, 392), 256, 0, stream>>>(x, W_v + wo, vcm, b_v + h * 128, ninv, 0, 1, 1, ROWS, 128, 512);
        vfft_k<<<1024, 512, 0, stream>>>(vcm, Ghat, RTc, Mv, M2c, RT2c);
        gemm_k<<<dim3(2, 392), 256, 0, stream>>>(x, W_u + wo, uB, b_u + h * 128, ninv, 0, 1, 2, ROWS, 128, 512);
        gemmW_k<<<dim3(8, 392), 256, 0, stream>>>(uB, vcm, W_o, b_o, x, out, h, h == 0);
    }
}

// Round 3
// 7873.126 us; speedup vs baseline: 1.1962x; 1.1962x over previous
//
#include <hip/hip_runtime.h>
#include <math.h>

// ---------------- problem sizes ----------------
#define NB 8
#define NN 56
#define POS 3136             // 56*56
#define ROWS 25088           // 8*3136
#define GR 111               // 2N-1
#define GROWS 12321          // 111*111
#define FREQ 16640           // per-channel spectrum floats: re 128x65 | im 128x65

// ---------------- workspace layout (float offsets), total 45.2 MB ----------------
#define OFF_RTC    0u         // 111x130   (gfft row-DFT)
#define OFF_MVT    14432u     // 112x256   (vfft fwd col-DFT, transposed)
#define OFF_MG     43104u     // 256x222   (gfft col-DFT)
#define OFF_M2T    99936u     // 256x112   (vfft inv col-DFT, transposed)
#define OFF_RT2T   128608u    // 56x136    (vfft inv row-DFT, transposed, re|pad|im)
#define OFF_RTC136 136224u    // 56x136    (vfft fwd row-DFT, re|pad|im)
#define OFF_NINV   143840u    // 25088
#define OFF_SINV   168928u    // 12336
#define OFF_TB     181264u    // 12321x512 rpe hidden
#define OFF_POOL   6489616u   // per-head pool, 4,816,896 floats
#define POOL_GCM   1577088u
#define POOL_GHAT  3211264u
#define POOL_U     3211264u
#define WS_FLOATS  11306512u  // ~45.23 MB

// ---------------- bf16 helpers ----------------
__device__ inline float bf2f(unsigned short b) {
    union { unsigned u; float f; } v; v.u = ((unsigned)b) << 16; return v.f;
}
__device__ inline unsigned short f2bf(float f) {
    union { float f; unsigned u; } v; v.f = f;
    unsigned r = v.u + 0x7FFF + ((v.u >> 16) & 1);
    return (unsigned short)(r >> 16);
}

__global__ void probe_k(float* out, float code) { out[0] = code; }

// =====================================================================
// constants. angle reduced exactly: (a*b) mod 128
// =====================================================================
__global__ void consts_k(float* RTc, float* MvT, float* Mg, float* M2cT,
                         float* RT2cT, float* RTc136) {
    int idx = blockIdx.x * 256 + threadIdx.x;
    const float STEP = 0.049087385212340526f; // 2*pi/128
    if (idx < 14430) { // RTc[q*130+col]: gfft row DFT (q up to 110)
        int q = idx / 130, col = idx % 130;
        int a = (col < 65) ? col : col - 65;
        float th = (float)((a * q) & 127) * STEP;
        RTc[idx] = (col < 65) ? cosf(th) : -sinf(th);
        return;
    }
    idx -= 14430;
    if (idx < 28672) { // MvT[s*256+r] = Mv[r][s]; fwd col DFT for v
        int s = idx / 256, r = idx % 256;
        int kp = (r < 128) ? r : r - 128;
        int sp = (s < 56) ? s : s - 56;
        float th = (float)((kp * sp) & 127) * STEP;
        float cv = cosf(th), sv = sinf(th);
        MvT[idx] = (r < 128) ? ((s < 56) ? cv : sv) : ((s < 56) ? -sv : cv);
        return;
    }
    idx -= 28672;
    if (idx < 56832) { // Mg[r*222+s]: gfft col DFT
        int r = idx / 222, s = idx % 222;
        int kp = (r < 128) ? r : r - 128;
        int sp = (s < 111) ? s : s - 111;
        float th = (float)((kp * sp) & 127) * STEP;
        float cv = cosf(th), sv = sinf(th);
        Mg[idx] = (r < 128) ? ((s < 111) ? cv : sv) : ((s < 111) ? -sv : cv);
        return;
    }
    idx -= 56832;
    if (idx < 28672) { // M2cT[s*112+r] = M2c[r][s]; inv col DFT rows a=p+55
        int s = idx / 112, r = idx % 112;
        int a = (r < 56) ? (r + 55) : (r - 1);
        int kp = (s < 128) ? s : s - 128;
        float th = (float)((kp * a) & 127) * STEP;
        float cv = cosf(th), sv = sinf(th);
        M2cT[idx] = (r < 56) ? ((s < 128) ? cv : -sv) : ((s < 128) ? sv : cv);
        return;
    }
    idx -= 28672;
    if (idx < 7616) { // RT2cT[b*136+col]: inv row DFT, cols b'=b+55, w/L^2 folded
        int b = idx / 136, col = idx % 136;
        float val = 0.f;
        if (col < 65 || (col >= 68 && col < 133)) {
            int kq = (col < 65) ? col : col - 68;
            float w = (kq == 0 || kq == 64) ? 1.f : 2.f;
            float th = (float)((kq * (b + 55)) & 127) * STEP;
            val = ((col < 65) ? cosf(th) : -sinf(th)) * w * (1.f / 16384.f);
        }
        RT2cT[idx] = val;
        return;
    }
    idx -= 7616;
    if (idx < 7616) { // RTc136[q*136+col]: fwd row DFT for v (q<56), re|pad|im
        int q = idx / 136, col = idx % 136;
        float val = 0.f;
        if (col < 65 || (col >= 68 && col < 133)) {
            int a = (col < 65) ? col : col - 68;
            float th = (float)((a * q) & 127) * STEP;
            val = (col < 65) ? cosf(th) : -sinf(th);
        }
        RTc136[idx] = val;
    }
}

// =====================================================================
// row L2 norms -> inverse simple-rms scale
// =====================================================================
__global__ void norms_k(const float* __restrict__ X, float* __restrict__ out, int rows) {
    int row = blockIdx.x * 4 + (threadIdx.x >> 6);
    int lane = threadIdx.x & 63;
    if (row >= rows) return;
    const float* p = X + (size_t)row * 512;
    float s = 0.f;
    #pragma unroll
    for (int i = 0; i < 8; ++i) { float v = p[lane + 64 * i]; s += v * v; }
    #pragma unroll
    for (int o = 32; o > 0; o >>= 1) s += __shfl_down(s, o, 64);
    if (lane == 0) out[row] = 1.f / (sqrtf(s) * 0.04419417382415922f + 1e-8f);
}

// =====================================================================
// t0 = coords @ rpe_in_w.T + rpe_in_b
// =====================================================================
__global__ void t0_k(const float* __restrict__ w, const float* __restrict__ b, float* __restrict__ out) {
    int idx = blockIdx.x * 256 + threadIdx.x;
    if (idx >= GROWS * 512) return;
    int r = idx >> 9, c = idx & 511;
    int i = r / 111, j = r % 111;
    float dp = (float)(i - 55), dq = (float)(j - 55);
    out[idx] = dp * w[c * 2] + dq * w[c * 2 + 1] + b[c];
}

// =====================================================================
// generic fp32 GEMM (unchanged from R2)
// =====================================================================
__global__ __launch_bounds__(256) void gemm_k(
    const float* __restrict__ A, const float* __restrict__ B,
    void* __restrict__ C, const float* __restrict__ bias,
    const float* __restrict__ in_scale, int in_relu, int act_silu,
    int out_mode, int M, int N, int K)
{
    __shared__ float As[16][64];
    __shared__ float Bs[16][64];
    const int tid = threadIdx.x;
    const int tx = tid & 15, ty = tid >> 4;
    const int row0 = blockIdx.y * 64, col0 = blockIdx.x * 64;
    const int lr = tid >> 2, lk = (tid & 3) << 2;
    float acc[4][4] = {};
    const int ar = row0 + lr;
    float s = 1.0f;
    if (in_scale && ar < M) s = in_scale[ar];
    const float* Arow = (ar < M) ? (A + (size_t)ar * K) : nullptr;
    const float* Brow = B + (size_t)(col0 + lr) * K;
    for (int k0 = 0; k0 < K; k0 += 16) {
        float4 av = make_float4(0.f, 0.f, 0.f, 0.f);
        if (Arow) av = *(const float4*)(Arow + k0 + lk);
        if (in_relu) {
            av.x = fmaxf(av.x, 0.f); av.y = fmaxf(av.y, 0.f);
            av.z = fmaxf(av.z, 0.f); av.w = fmaxf(av.w, 0.f);
        }
        As[lk + 0][lr] = av.x * s; As[lk + 1][lr] = av.y * s;
        As[lk + 2][lr] = av.z * s; As[lk + 3][lr] = av.w * s;
        float4 bv = *(const float4*)(Brow + k0 + lk);
        Bs[lk + 0][lr] = bv.x; Bs[lk + 1][lr] = bv.y;
        Bs[lk + 2][lr] = bv.z; Bs[lk + 3][lr] = bv.w;
        __syncthreads();
        #pragma unroll
        for (int kk = 0; kk < 16; ++kk) {
            const float4 a4 = *(const float4*)&As[kk][ty << 2];
            const float4 b4 = *(const float4*)&Bs[kk][tx << 2];
            float avv[4] = {a4.x, a4.y, a4.z, a4.w};
            float bvv[4] = {b4.x, b4.y, b4.z, b4.w};
            #pragma unroll
            for (int i = 0; i < 4; ++i)
                #pragma unroll
                for (int j = 0; j < 4; ++j)
                    acc[i][j] = fmaf(avv[i], bvv[j], acc[i][j]);
        }
        __syncthreads();
    }
    #pragma unroll
    for (int i = 0; i < 4; ++i) {
        int r = row0 + (ty << 2) + i;
        if (r >= M) break;
        #pragma unroll
        for (int j = 0; j < 4; ++j) {
            int c = col0 + (tx << 2) + j;
            float v = acc[i][j] + bias[c];
            if (act_silu) v = v / (1.f + expf(-v));
            if (out_mode == 0) {
                ((float*)C)[(size_t)r * N + c] = v;
            } else if (out_mode == 1) {
                int b = r / POS, pos = r - b * POS;
                ((float*)C)[((size_t)(b * 128 + c)) * POS + pos] = v;
            } else {
                ((unsigned short*)C)[(size_t)r * N + c] = f2bf(v);
            }
        }
    }
}

// =====================================================================
// transpose: src [nrows x 128] -> dst [128 x nrows]
// =====================================================================
__global__ void transpose128_k(const float* __restrict__ src, float* __restrict__ dst, int nrows) {
    __shared__ float tile[32][33];
    int r0 = blockIdx.x * 32, c0 = blockIdx.y * 32;
    int tx = threadIdx.x, ty = threadIdx.y;
    #pragma unroll
    for (int i = 0; i < 32; i += 8) {
        int r = r0 + ty + i;
        if (r < nrows) tile[ty + i][tx] = src[(size_t)r * 128 + c0 + tx];
    }
    __syncthreads();
    int r = r0 + tx;
    if (r < nrows) {
        #pragma unroll
        for (int i = 0; i < 32; i += 8)
            dst[(size_t)(c0 + ty + i) * nrows + r] = tile[tx][ty + i];
    }
}

// =====================================================================
// g spectrum (one head) — unchanged
// =====================================================================
__global__ __launch_bounds__(512) void gfft_k(
    const float* __restrict__ gcm, const float* __restrict__ RTc,
    const float* __restrict__ Mg, float* __restrict__ Ghat)
{
    __shared__ float Gs[GROWS];
    __shared__ float Tg[222 * 17];
    int tid = threadIdx.x, d = blockIdx.x, kq0 = blockIdx.y * 17;
    int C = min(17, 65 - kq0), C2 = 2 * C;
    const float* src = gcm + (size_t)d * GROWS;
    for (int i = tid; i < GROWS; i += 512) Gs[i] = src[i];
    float* gout = Ghat + (size_t)d * FREQ;
    __syncthreads();
    for (int o = tid; o < 111 * C2; o += 512) {
        int p = o / C2, cc = o % C2;
        int col = (cc < C) ? (kq0 + cc) : (65 + kq0 + (cc - C));
        const float* gp = Gs + p * 111;
        const float* rp = RTc + col;
        float acc = 0.f;
        #pragma unroll 8
        for (int q = 0; q < 111; ++q) acc = fmaf(gp[q], rp[q * 130], acc);
        Tg[p * C2 + cc] = acc;
    }
    __syncthreads();
    for (int o = tid; o < 128 * C; o += 512) {
        int r = o / C, c = o % C;
        const float* m1 = Mg + (size_t)r * 222;
        const float* m2 = Mg + (size_t)(r + 128) * 222;
        float a1 = 0.f, a2 = 0.f;
        #pragma unroll 8
        for (int ss = 0; ss < 111; ++ss) {
            float tre = Tg[ss * C2 + c];
            a1 = fmaf(m1[ss], tre, a1); a2 = fmaf(m2[ss], tre, a2);
        }
        #pragma unroll 8
        for (int ss = 0; ss < 111; ++ss) {
            float tim = Tg[ss * C2 + C + c];
            a1 = fmaf(m1[111 + ss], tim, a1); a2 = fmaf(m2[111 + ss], tim, a2);
        }
        gout[r * 65 + kq0 + c] = a1;
        gout[8320 + r * 65 + kq0 + c] = a2;
    }
}

// =====================================================================
// v conv (one head, in-place), register-tiled fp32 rewrite.
// Per block: one channel (d,b). Chunks kq0={0,32} (C=32) + Nyquist tail.
// LDS: Vs 12.5K + Tq[112][36] 16.1K + Vh[256][32] 32.8K = 60 KB (2 blk/CU)
// Ys accumulator in registers (7/thread).
// =====================================================================
__global__ __launch_bounds__(512) void vfft_k(
    float* __restrict__ vcm, const float* __restrict__ Ghat,
    const float* __restrict__ RTc136, const float* __restrict__ MvT,
    const float* __restrict__ M2cT, const float* __restrict__ RT2cT)
{
    __shared__ float Vs[POS];
    __shared__ float Tq[112 * 36];
    __shared__ float Vh[256 * 32];
    const int tid = threadIdx.x;
    const int d = blockIdx.x >> 3, b = blockIdx.x & 7;
    float* chan = vcm + (size_t)(b * 128 + d) * POS;
    float ys[7];
    int p5[7], b5[7];
    #pragma unroll
    for (int i = 0; i < 7; ++i) {
        ys[i] = 0.f;
        int o = tid + 512 * i;
        p5[i] = o / 56; b5[i] = o - p5[i] * 56;
    }
    for (int i = tid; i < POS; i += 512) Vs[i] = chan[i];
    const float* gre = Ghat + (size_t)d * FREQ;

    for (int ck = 0; ck < 2; ++ck) {
        const int kq0 = ck * 32;
        __syncthreads();
        // ---- S1: forward row DFT: Tq[p][c](re), Tq[56+p][c](im) ----
        if (tid < 448) {
            const int region = tid & 1;
            const int t2 = tid >> 1;
            const int p0 = (t2 >> 3) << 1;
            const int c0 = (t2 & 7) << 2;
            const float* rbase = RTc136 + (region ? 68 : 0) + kq0 + c0;
            const float* v0 = Vs + p0 * 56;
            const float* v1 = v0 + 56;
            float a0x=0,a0y=0,a0z=0,a0w=0, a1x=0,a1y=0,a1z=0,a1w=0;
            for (int q = 0; q < 56; ++q) {
                float4 rv = *(const float4*)(rbase + q * 136);
                float x0 = v0[q], x1 = v1[q];
                a0x = fmaf(x0, rv.x, a0x); a0y = fmaf(x0, rv.y, a0y);
                a0z = fmaf(x0, rv.z, a0z); a0w = fmaf(x0, rv.w, a0w);
                a1x = fmaf(x1, rv.x, a1x); a1y = fmaf(x1, rv.y, a1y);
                a1z = fmaf(x1, rv.z, a1z); a1w = fmaf(x1, rv.w, a1w);
            }
            const int pr = region * 56 + p0;
            *(float4*)&Tq[pr * 36 + c0]       = make_float4(a0x, a0y, a0z, a0w);
            *(float4*)&Tq[(pr + 1) * 36 + c0] = make_float4(a1x, a1y, a1z, a1w);
        }
        __syncthreads();
        // ---- S2: forward col DFT: Vh[r][c] = sum_s MvT[s][r]*Tq[s][c] ----
        {
            const int r0 = (tid >> 3) << 2;
            const int c0 = (tid & 7) << 2;
            float acc[4][4] = {};
            for (int s = 0; s < 112; ++s) {
                float4 m = *(const float4*)(MvT + s * 256 + r0);
                float4 t = *(const float4*)&Tq[s * 36 + c0];
                acc[0][0]=fmaf(m.x,t.x,acc[0][0]); acc[0][1]=fmaf(m.x,t.y,acc[0][1]);
                acc[0][2]=fmaf(m.x,t.z,acc[0][2]); acc[0][3]=fmaf(m.x,t.w,acc[0][3]);
                acc[1][0]=fmaf(m.y,t.x,acc[1][0]); acc[1][1]=fmaf(m.y,t.y,acc[1][1]);
                acc[1][2]=fmaf(m.y,t.z,acc[1][2]); acc[1][3]=fmaf(m.y,t.w,acc[1][3]);
                acc[2][0]=fmaf(m.z,t.x,acc[2][0]); acc[2][1]=fmaf(m.z,t.y,acc[2][1]);
                acc[2][2]=fmaf(m.z,t.z,acc[2][2]); acc[2][3]=fmaf(m.z,t.w,acc[2][3]);
                acc[3][0]=fmaf(m.w,t.x,acc[3][0]); acc[3][1]=fmaf(m.w,t.y,acc[3][1]);
                acc[3][2]=fmaf(m.w,t.z,acc[3][2]); acc[3][3]=fmaf(m.w,t.w,acc[3][3]);
            }
            #pragma unroll
            for (int i = 0; i < 4; ++i)
                *(float4*)&Vh[(r0 + i) * 32 + c0] =
                    make_float4(acc[i][0], acc[i][1], acc[i][2], acc[i][3]);
        }
        __syncthreads();
        // ---- S3: complex multiply with Ghat ----
        #pragma unroll
        for (int i = 0; i < 8; ++i) {
            int o = tid + 512 * i;
            int kp = o >> 5, c = o & 31;
            float vr = Vh[kp * 32 + c], vi = Vh[(128 + kp) * 32 + c];
            int gi_ = kp * 65 + kq0 + c;
            float gr = gre[gi_], gm = gre[8320 + gi_];
            Vh[kp * 32 + c] = vr * gr - vi * gm;
            Vh[(128 + kp) * 32 + c] = vr * gm + vi * gr;
        }
        __syncthreads();
        // ---- S4: inverse col DFT: Q[r][c] = sum_s M2cT[s][r]*Vh[s][c] ----
        if (tid < 448) {
            const int r0 = (tid >> 3) << 1;
            const int c0 = (tid & 7) << 2;
            float acc[2][4] = {};
            for (int s = 0; s < 256; ++s) {
                float2 m = *(const float2*)(M2cT + s * 112 + r0);
                float4 v = *(const float4*)&Vh[s * 32 + c0];
                acc[0][0]=fmaf(m.x,v.x,acc[0][0]); acc[0][1]=fmaf(m.x,v.y,acc[0][1]);
                acc[0][2]=fmaf(m.x,v.z,acc[0][2]); acc[0][3]=fmaf(m.x,v.w,acc[0][3]);
                acc[1][0]=fmaf(m.y,v.x,acc[1][0]); acc[1][1]=fmaf(m.y,v.y,acc[1][1]);
                acc[1][2]=fmaf(m.y,v.z,acc[1][2]); acc[1][3]=fmaf(m.y,v.w,acc[1][3]);
            }
            *(float4*)&Tq[r0 * 36 + c0]       = make_float4(acc[0][0],acc[0][1],acc[0][2],acc[0][3]);
            *(float4*)&Tq[(r0 + 1) * 36 + c0] = make_float4(acc[1][0],acc[1][1],acc[1][2],acc[1][3]);
        }
        __syncthreads();
        // ---- S5: inverse row DFT, accumulate into ys ----
        #pragma unroll
        for (int i = 0; i < 7; ++i) {
            if (i < 6 || tid < 64) {
                const float* rt = RT2cT + b5[i] * 136 + kq0;
                const float* q1 = Tq + p5[i] * 36;
                const float* q2 = Tq + (56 + p5[i]) * 36;
                float acc = ys[i];
                #pragma unroll
                for (int cq = 0; cq < 8; ++cq) {
                    float4 rr = *(const float4*)(rt + 4 * cq);
                    float4 ri = *(const float4*)(rt + 68 + 4 * cq);
                    float4 qa = *(const float4*)(q1 + 4 * cq);
                    float4 qb = *(const float4*)(q2 + 4 * cq);
                    acc = fmaf(qa.x, rr.x, acc); acc = fmaf(qa.y, rr.y, acc);
                    acc = fmaf(qa.z, rr.z, acc); acc = fmaf(qa.w, rr.w, acc);
                    acc = fmaf(qb.x, ri.x, acc); acc = fmaf(qb.y, ri.y, acc);
                    acc = fmaf(qb.z, ri.z, acc); acc = fmaf(qb.w, ri.w, acc);
                }
                ys[i] = acc;
            }
        }
    }
    // ---- Nyquist tail: kq = 64 ----
    __syncthreads();
    if (tid < 56) {        // S1t: Tre64[p] = sum_q v*(-1)^q  (im = 0)
        const float* vp = Vs + tid * 56;
        float acc = 0.f;
        #pragma unroll 4
        for (int q = 0; q < 56; q += 2) acc += vp[q] - vp[q + 1];
        Tq[tid * 36] = acc;
    }
    __syncthreads();
    if (tid < 256) {       // S2t
        float acc = 0.f;
        for (int s = 0; s < 56; ++s)
            acc = fmaf(MvT[s * 256 + tid], Tq[s * 36], acc);
        Vh[tid * 32] = acc;
    }
    __syncthreads();
    if (tid < 128) {       // S3t
        float vr = Vh[tid * 32], vi = Vh[(128 + tid) * 32];
        int gi_ = tid * 65 + 64;
        float gr = gre[gi_], gm = gre[8320 + gi_];
        Vh[tid * 32] = vr * gr - vi * gm;
        Vh[(128 + tid) * 32] = vr * gm + vi * gr;
    }
    __syncthreads();
    if (tid < 112) {       // S4t
        float acc = 0.f;
        for (int s = 0; s < 256; ++s)
            acc = fmaf(M2cT[s * 112 + tid], Vh[s * 32], acc);
        Tq[tid * 36] = acc;
    }
    __syncthreads();
    #pragma unroll
    for (int i = 0; i < 7; ++i) {
        if (i < 6 || tid < 64) {
            float r1 = RT2cT[b5[i] * 136 + 64];
            float r2 = RT2cT[b5[i] * 136 + 132];
            ys[i] = fmaf(Tq[p5[i] * 36], r1, fmaf(Tq[(56 + p5[i]) * 36], r2, ys[i]));
        }
    }
    #pragma unroll
    for (int i = 0; i < 7; ++i)
        if (i < 6 || tid < 64) chan[tid + 512 * i] = ys[i];
}

// =====================================================================
// final projection, one head, split-K accumulate (unchanged)
// =====================================================================
__global__ __launch_bounds__(256) void gemmW_k(
    const unsigned short* __restrict__ u, const float* __restrict__ ycm,
    const float* __restrict__ Wo, const float* __restrict__ bo,
    const float* __restrict__ x, float* __restrict__ out, int h, int first)
{
    __shared__ float As[16][64];
    __shared__ float Bs[16][64];
    const int tid = threadIdx.x;
    const int tx = tid & 15, ty = tid >> 4;
    const int row0 = blockIdx.y * 64, col0 = blockIdx.x * 64;
    const int lr = tid >> 2, lk = (tid & 3) << 2;
    const int ar = row0 + lr;
    const int b = ar / POS, pos = ar - b * POS;
    const unsigned short* urow = u + (size_t)ar * 128;
    const float* ybase = ycm + (size_t)(b * 128) * POS + pos;
    const float* Brow = Wo + (size_t)(col0 + lr) * 1024 + h * 128;
    float acc[4][4] = {};
    for (int k0 = 0; k0 < 128; k0 += 16) {
        ushort4 uv = *(const ushort4*)(urow + k0 + lk);
        float y0 = ybase[(size_t)(k0 + lk + 0) * POS];
        float y1 = ybase[(size_t)(k0 + lk + 1) * POS];
        float y2 = ybase[(size_t)(k0 + lk + 2) * POS];
        float y3 = ybase[(size_t)(k0 + lk + 3) * POS];
        As[lk + 0][lr] = bf2f(uv.x) * y0;
        As[lk + 1][lr] = bf2f(uv.y) * y1;
        As[lk + 2][lr] = bf2f(uv.z) * y2;
        As[lk + 3][lr] = bf2f(uv.w) * y3;
        float4 bv = *(const float4*)(Brow + k0 + lk);
        Bs[lk + 0][lr] = bv.x; Bs[lk + 1][lr] = bv.y;
        Bs[lk + 2][lr] = bv.z; Bs[lk + 3][lr] = bv.w;
        __syncthreads();
        #pragma unroll
        for (int kk = 0; kk < 16; ++kk) {
            const float4 a4 = *(const float4*)&As[kk][ty << 2];
            const float4 b4 = *(const float4*)&Bs[kk][tx << 2];
            float avv[4] = {a4.x, a4.y, a4.z, a4.w};
            float bvv[4] = {b4.x, b4.y, b4.z, b4.w};
            #pragma unroll
            for (int i = 0; i < 4; ++i)
                #pragma unroll
                for (int j = 0; j < 4; ++j)
                    acc[i][j] = fmaf(avv[i], bvv[j], acc[i][j]);
        }
        __syncthreads();
    }
    #pragma unroll
    for (int i = 0; i < 4; ++i) {
        int r = row0 + (ty << 2) + i;
        #pragma unroll
        for (int j = 0; j < 4; ++j) {
            int c = col0 + (tx << 2) + j;
            size_t oi = (size_t)r * 512 + c;
            float v = acc[i][j];
            v += first ? (bo[c] + x[oi]) : out[oi];
            out[oi] = v;
        }
    }
}

// =====================================================================
extern "C" void kernel_launch(void* const* d_in, const int* in_sizes, int n_in,
                              void* d_out, int out_size, void* d_ws, size_t ws_size,
                              hipStream_t stream) {
    (void)in_sizes; (void)n_in; (void)out_size;
    const float* x         = (const float*)d_in[0];
    const float* W_u       = (const float*)d_in[1];
    const float* b_u       = (const float*)d_in[2];
    const float* W_v       = (const float*)d_in[3];
    const float* b_v       = (const float*)d_in[4];
    const float* W_o       = (const float*)d_in[5];
    const float* b_o       = (const float*)d_in[6];
    const float* rpe_in_w  = (const float*)d_in[7];
    const float* rpe_in_b  = (const float*)d_in[8];
    const float* rpe_h_w   = (const float*)d_in[9];
    const float* rpe_h_b   = (const float*)d_in[10];
    const float* rpe_out_w = (const float*)d_in[11];
    const float* rpe_out_b = (const float*)d_in[12];
    float* out = (float*)d_out;

    if (ws_size < (size_t)WS_FLOATS * 4) {
        probe_k<<<1, 1, 0, stream>>>(out, 1000.0f + (float)((double)ws_size * 1e-6));
        return;
    }
    float* ws     = (float*)d_ws;
    float* RTc    = ws + OFF_RTC;
    float* MvT    = ws + OFF_MVT;
    float* Mg     = ws + OFF_MG;
    float* M2cT   = ws + OFF_M2T;
    float* RT2cT  = ws + OFF_RT2T;
    float* RTc136 = ws + OFF_RTC136;
    float* ninv   = ws + OFF_NINV;
    float* sinv   = ws + OFF_SINV;
    float* tB     = ws + OFF_TB;
    float* pool   = ws + OFF_POOL;
    float* g_row  = pool;
    float* g_cm   = pool + POOL_GCM;
    float* vcm    = pool;
    float* Ghat   = pool + POOL_GHAT;
    unsigned short* uB = (unsigned short*)(pool + POOL_U);
    float* tA     = out;   // rpe ping in d_out; dead before head 0 writes out

    consts_k<<<562, 256, 0, stream>>>(RTc, MvT, Mg, M2cT, RT2cT, RTc136);

    // ---- RPE MLP hidden layers ----
    t0_k<<<24642, 256, 0, stream>>>(rpe_in_w, rpe_in_b, tA);
    norms_k<<<3081, 256, 0, stream>>>(tA, sinv, GROWS);
    gemm_k<<<dim3(8, 193), 256, 0, stream>>>(tA, rpe_h_w,          tB, rpe_h_b,        sinv, 1, 0, 0, GROWS, 512, 512);
    norms_k<<<3081, 256, 0, stream>>>(tB, sinv, GROWS);
    gemm_k<<<dim3(8, 193), 256, 0, stream>>>(tB, rpe_h_w + 262144, tA, rpe_h_b + 512,  sinv, 1, 0, 0, GROWS, 512, 512);
    norms_k<<<3081, 256, 0, stream>>>(tA, sinv, GROWS);
    gemm_k<<<dim3(8, 193), 256, 0, stream>>>(tA, rpe_h_w + 524288, tB, rpe_h_b + 1024, sinv, 1, 0, 0, GROWS, 512, 512);
    norms_k<<<3081, 256, 0, stream>>>(tB, sinv, GROWS);

    norms_k<<<6272, 256, 0, stream>>>(x, ninv, ROWS);

    // ---- per-head main path ----
    for (int h = 0; h < 8; ++h) {
        const size_t wo = (size_t)h * 128 * 512;
        gemm_k<<<dim3(2, 193), 256, 0, stream>>>(tB, rpe_out_w + wo, g_row, rpe_out_b + h * 128, sinv, 1, 0, 0, GROWS, 128, 512);
        transpose128_k<<<dim3(386, 4), dim3(32, 8), 0, stream>>>(g_row, g_cm, GROWS);
        gfft_k<<<dim3(128, 4), 512, 0, stream>>>(g_cm, RTc, Mg, Ghat);
        gemm_k<<<dim3(2, 392), 256, 0, stream>>>(x, W_v + wo, vcm, b_v + h * 128, ninv, 0, 1, 1, ROWS, 128, 512);
        vfft_k<<<1024, 512, 0, stream>>>(vcm, Ghat, RTc136, MvT, M2cT, RT2cT);
        gemm_k<<<dim3(2, 392), 256, 0, stream>>>(x, W_u + wo, uB, b_u + h * 128, ninv, 0, 1, 2, ROWS, 128, 512);
        gemmW_k<<<dim3(8, 392), 256, 0, stream>>>(uB, vcm, W_o, b_o, x, out, h, h == 0);
    }
}

// Round 4
// 6677.352 us; speedup vs baseline: 1.4105x; 1.1791x over previous
//
#include <hip/hip_runtime.h>
#include <math.h>

// ---------------- problem sizes ----------------
#define NB 8
#define NN 56
#define POS 3136             // 56*56
#define ROWS 25088           // 8*3136
#define GR 111               // 2N-1
#define GROWS 12321          // 111*111
#define FREQ 16640           // per-channel spectrum floats: re 128x65 | im 128x65

// ---------------- workspace layout (float offsets), total 40.5 MB ----------------
#define OFF_RTC    0u         // 111x130   (gfft row-DFT)
#define OFF_MVT    14432u     // 112x256   (vfft fwd col-DFT, transposed)
#define OFF_MG     43104u     // 256x222   (gfft col-DFT)
#define OFF_M2T    99936u     // 256x112   (vfft inv col-DFT, transposed)
#define OFF_RT2T   128608u    // 56x136    (vfft inv row-DFT, re|pad|im)
#define OFF_RTC136 136224u    // 56x136    (vfft fwd row-DFT, re|pad|im)
#define OFF_NINV   143840u    // 25088
#define OFF_SINV   168928u    // 12336
#define OFF_WB     181264u    // bf16 weights, 2,883,584 ushorts = 1,441,792 fl
#define OFF_TB16   1623056u   // 12321x512 bf16 (relu*scale of final rpe hidden)
#define OFF_POOL   4777232u   // vcm 3,211,264 fl | Ghat 2,129,920 fl
#define POOL_GHAT  3211264u
#define WS_FLOATS  10118416u  // 40.47 MB
// bf16 weight sub-offsets (ushort units inside OFF_WB)
#define WB_WU  0u
#define WB_WV  524288u
#define WB_WO  1048576u
#define WB_WH  1572864u
#define WB_WRO 2359296u
// rpe fp32 ping-pong lives in d_out (dead before head 0's out write):
//   tA = out, tBf = out + 6,308,352
// g_row/g_cm alias vcm (dead before v written); u16 aliases Ghat (dead after vfft)

typedef __attribute__((ext_vector_type(8))) short bf8_t;         // 8 bf16 (as i16)
typedef __attribute__((ext_vector_type(8))) unsigned short us8_t;
typedef __attribute__((ext_vector_type(4))) float f4_t;

// ---------------- bf16 helpers ----------------
__device__ inline float bf2f(unsigned short b) {
    union { unsigned u; float f; } v; v.u = ((unsigned)b) << 16; return v.f;
}
__device__ inline unsigned short f2bf(float f) {
    union { float f; unsigned u; } v; v.f = f;
    unsigned r = v.u + 0x7FFF + ((v.u >> 16) & 1);
    return (unsigned short)(r >> 16);
}

__global__ void probe_k(float* out, float code) { out[0] = code; }

// =====================================================================
// constants. angle reduced exactly: (a*b) mod 128
// =====================================================================
__global__ void consts_k(float* RTc, float* MvT, float* Mg, float* M2cT,
                         float* RT2cT, float* RTc136) {
    int idx = blockIdx.x * 256 + threadIdx.x;
    const float STEP = 0.049087385212340526f; // 2*pi/128
    if (idx < 14430) { // RTc[q*130+col]: gfft row DFT (q up to 110)
        int q = idx / 130, col = idx % 130;
        int a = (col < 65) ? col : col - 65;
        float th = (float)((a * q) & 127) * STEP;
        RTc[idx] = (col < 65) ? cosf(th) : -sinf(th);
        return;
    }
    idx -= 14430;
    if (idx < 28672) { // MvT[s*256+r]
        int s = idx / 256, r = idx % 256;
        int kp = (r < 128) ? r : r - 128;
        int sp = (s < 56) ? s : s - 56;
        float th = (float)((kp * sp) & 127) * STEP;
        float cv = cosf(th), sv = sinf(th);
        MvT[idx] = (r < 128) ? ((s < 56) ? cv : sv) : ((s < 56) ? -sv : cv);
        return;
    }
    idx -= 28672;
    if (idx < 56832) { // Mg[r*222+s]
        int r = idx / 222, s = idx % 222;
        int kp = (r < 128) ? r : r - 128;
        int sp = (s < 111) ? s : s - 111;
        float th = (float)((kp * sp) & 127) * STEP;
        float cv = cosf(th), sv = sinf(th);
        Mg[idx] = (r < 128) ? ((s < 111) ? cv : sv) : ((s < 111) ? -sv : cv);
        return;
    }
    idx -= 56832;
    if (idx < 28672) { // M2cT[s*112+r]
        int s = idx / 112, r = idx % 112;
        int a = (r < 56) ? (r + 55) : (r - 1);
        int kp = (s < 128) ? s : s - 128;
        float th = (float)((kp * a) & 127) * STEP;
        float cv = cosf(th), sv = sinf(th);
        M2cT[idx] = (r < 56) ? ((s < 128) ? cv : -sv) : ((s < 128) ? sv : cv);
        return;
    }
    idx -= 28672;
    if (idx < 7616) { // RT2cT[b*136+col]
        int b = idx / 136, col = idx % 136;
        float val = 0.f;
        if (col < 65 || (col >= 68 && col < 133)) {
            int kq = (col < 65) ? col : col - 68;
            float w = (kq == 0 || kq == 64) ? 1.f : 2.f;
            float th = (float)((kq * (b + 55)) & 127) * STEP;
            val = ((col < 65) ? cosf(th) : -sinf(th)) * w * (1.f / 16384.f);
        }
        RT2cT[idx] = val;
        return;
    }
    idx -= 7616;
    if (idx < 7616) { // RTc136[q*136+col]
        int q = idx / 136, col = idx % 136;
        float val = 0.f;
        if (col < 65 || (col >= 68 && col < 133)) {
            int a = (col < 65) ? col : col - 68;
            float th = (float)((a * q) & 127) * STEP;
            val = (col < 65) ? cosf(th) : -sinf(th);
        }
        RTc136[idx] = val;
    }
}

// =====================================================================
// row L2 norms -> inverse simple-rms scale, D=512
// =====================================================================
__global__ void norms_k(const float* __restrict__ X, float* __restrict__ out, int rows) {
    int row = blockIdx.x * 4 + (threadIdx.x >> 6);
    int lane = threadIdx.x & 63;
    if (row >= rows) return;
    const float* p = X + (size_t)row * 512;
    float s = 0.f;
    #pragma unroll
    for (int i = 0; i < 8; ++i) { float v = p[lane + 64 * i]; s += v * v; }
    #pragma unroll
    for (int o = 32; o > 0; o >>= 1) s += __shfl_down(s, o, 64);
    if (lane == 0) out[row] = 1.f / (sqrtf(s) * 0.04419417382415922f + 1e-8f);
}

// =====================================================================
// t0 = coords @ rpe_in_w.T + rpe_in_b
// =====================================================================
__global__ void t0_k(const float* __restrict__ w, const float* __restrict__ b, float* __restrict__ out) {
    int idx = blockIdx.x * 256 + threadIdx.x;
    if (idx >= GROWS * 512) return;
    int r = idx >> 9, c = idx & 511;
    int i = r / 111, j = r % 111;
    float dp = (float)(i - 55), dq = (float)(j - 55);
    out[idx] = dp * w[c * 2] + dq * w[c * 2 + 1] + b[c];
}

// =====================================================================
// converts
// =====================================================================
__global__ void convw_k(const float* __restrict__ src, unsigned short* __restrict__ dst, int n) {
    int i = blockIdx.x * 256 + threadIdx.x;
    if (i < n) dst[i] = f2bf(src[i]);
}
__global__ void convt_k(const float* __restrict__ t, const float* __restrict__ sinv,
                        unsigned short* __restrict__ dst) {
    int i = blockIdx.x * 256 + threadIdx.x;
    if (i >= GROWS * 512) return;
    int r = i >> 9;
    dst[i] = f2bf(fmaxf(t[i], 0.f) * sinv[r]);
}

// =====================================================================
// bf16 MFMA GEMM: C[M,N] = epilogue( A'[M,K] @ B[N,K]^T )
//  amode 0: A fp32 rm, A' = (relu_in?relu(A):A) * scale[row], cvt bf16 at staging
//  amode 1: A bf16 rm
//  amode 2: A' = bf16(u_bf16[r][k] * yv[((r/POS)*128+k)*POS + r%POS])  (gating)
//  emode 0: fp32 rm, +bias
//  emode 1: fp32 channel-major, +bias, silu   (N==128)
//  emode 2: bf16 rm, +bias, silu
//  emode 3: out[r*512+c] = acc + (first ? bias[c]+xres : out)   (split-K accum)
// 128x128 tile, 256 thr (4 waves, 2x2 of 64x64), BK=32, v_mfma_f32_16x16x32_bf16
// =====================================================================
__global__ __launch_bounds__(256) void mgemm_k(
    const void* __restrict__ Aptr, const unsigned short* __restrict__ B, int ldb,
    const float* __restrict__ yv, const float* __restrict__ scale,
    int relu_in, int amode,
    void* __restrict__ Cptr, const float* __restrict__ bias,
    const float* __restrict__ xres, float* __restrict__ outAcc, int first,
    int emode, int M, int N, int K)
{
    __shared__ __align__(16) unsigned short As[4096];   // [chunk 0..3][m 0..127][8]
    __shared__ __align__(16) unsigned short Bs[4096];
    const int t = threadIdx.x;
    const int lane = t & 63;
    const int quad = lane >> 4, ln = lane & 15;
    const int wave = t >> 6;
    const int wm = (wave >> 1) << 6, wn = (wave & 1) << 6;
    const int row0 = blockIdx.y << 7, col0 = blockIdx.x << 7;
    const int sc = t & 3;          // k-chunk
    const int sm = t >> 2;         // row (+64 for rep 1)
    const float* Af = (const float*)Aptr;
    const unsigned short* Au = (const unsigned short*)Aptr;
    f4_t acc[4][4];
    #pragma unroll
    for (int i = 0; i < 4; ++i)
        #pragma unroll
        for (int j = 0; j < 4; ++j)
            acc[i][j] = (f4_t){0.f, 0.f, 0.f, 0.f};

    for (int k0 = 0; k0 < K; k0 += 32) {
        #pragma unroll
        for (int rep = 0; rep < 2; ++rep) {           // ---- stage A ----
            const int m = sm + (rep << 6);
            const int am = row0 + m;
            us8_t av = {0, 0, 0, 0, 0, 0, 0, 0};
            if (am < M) {
                if (amode == 0) {
                    const float s = scale ? scale[am] : 1.f;
                    const float* ap = Af + (size_t)am * K + k0 + (sc << 3);
                    float4 f1 = *(const float4*)ap;
                    float4 f2 = *(const float4*)(ap + 4);
                    if (relu_in) {
                        f1.x = fmaxf(f1.x, 0.f); f1.y = fmaxf(f1.y, 0.f);
                        f1.z = fmaxf(f1.z, 0.f); f1.w = fmaxf(f1.w, 0.f);
                        f2.x = fmaxf(f2.x, 0.f); f2.y = fmaxf(f2.y, 0.f);
                        f2.z = fmaxf(f2.z, 0.f); f2.w = fmaxf(f2.w, 0.f);
                    }
                    av[0] = f2bf(f1.x * s); av[1] = f2bf(f1.y * s);
                    av[2] = f2bf(f1.z * s); av[3] = f2bf(f1.w * s);
                    av[4] = f2bf(f2.x * s); av[5] = f2bf(f2.y * s);
                    av[6] = f2bf(f2.z * s); av[7] = f2bf(f2.w * s);
                } else if (amode == 1) {
                    av = *(const us8_t*)(Au + (size_t)am * K + k0 + (sc << 3));
                } else {
                    const unsigned short* up = Au + (size_t)am * K + k0 + (sc << 3);
                    const int bb = am / POS, pos = am - bb * POS;
                    const float* yb = yv + ((size_t)(bb * 128 + k0 + (sc << 3))) * POS + pos;
                    #pragma unroll
                    for (int j = 0; j < 8; ++j)
                        av[j] = f2bf(bf2f(up[j]) * yb[(size_t)j * POS]);
                }
            }
            *(us8_t*)&As[(sc << 10) + (m << 3)] = av;
        }
        #pragma unroll
        for (int rep = 0; rep < 2; ++rep) {           // ---- stage B ----
            const int n = sm + (rep << 6);
            us8_t bv = *(const us8_t*)(B + (size_t)(col0 + n) * ldb + k0 + (sc << 3));
            *(us8_t*)&Bs[(sc << 10) + (n << 3)] = bv;
        }
        __syncthreads();
        bf8_t af[4], bfr[4];
        #pragma unroll
        for (int i = 0; i < 4; ++i)
            af[i] = *(const bf8_t*)&As[(quad << 10) + ((wm + (i << 4) + ln) << 3)];
        #pragma unroll
        for (int i = 0; i < 4; ++i)
            bfr[i] = *(const bf8_t*)&Bs[(quad << 10) + ((wn + (i << 4) + ln) << 3)];
        #pragma unroll
        for (int i = 0; i < 4; ++i)
            #pragma unroll
            for (int j = 0; j < 4; ++j)
                acc[i][j] = __builtin_amdgcn_mfma_f32_16x16x32_bf16(af[i], bfr[j], acc[i][j], 0, 0, 0);
        __syncthreads();
    }
    // ---- epilogue ----
    #pragma unroll
    for (int i = 0; i < 4; ++i) {
        #pragma unroll
        for (int j = 0; j < 4; ++j) {
            #pragma unroll
            for (int rr = 0; rr < 4; ++rr) {
                const int r = row0 + wm + (i << 4) + (quad << 2) + rr;
                const int c = col0 + wn + (j << 4) + ln;
                if (r >= M) continue;
                float v = acc[i][j][rr];
                if (emode == 0) {
                    v += bias[c];
                    ((float*)Cptr)[(size_t)r * N + c] = v;
                } else if (emode == 1) {
                    v += bias[c]; v = v / (1.f + expf(-v));
                    const int bb = r / POS, pos = r - bb * POS;
                    ((float*)Cptr)[((size_t)(bb * 128 + c)) * POS + pos] = v;
                } else if (emode == 2) {
                    v += bias[c]; v = v / (1.f + expf(-v));
                    ((unsigned short*)Cptr)[(size_t)r * N + c] = f2bf(v);
                } else {
                    const size_t oi = (size_t)r * 512 + c;
                    v += first ? (bias[c] + xres[oi]) : outAcc[oi];
                    outAcc[oi] = v;
                }
            }
        }
    }
}

// =====================================================================
// transpose: src [nrows x 128] -> dst [128 x nrows]   (g path, fp32)
// =====================================================================
__global__ void transpose128_k(const float* __restrict__ src, float* __restrict__ dst, int nrows) {
    __shared__ float tile[32][33];
    int r0 = blockIdx.x * 32, c0 = blockIdx.y * 32;
    int tx = threadIdx.x, ty = threadIdx.y;
    #pragma unroll
    for (int i = 0; i < 32; i += 8) {
        int r = r0 + ty + i;
        if (r < nrows) tile[ty + i][tx] = src[(size_t)r * 128 + c0 + tx];
    }
    __syncthreads();
    int r = r0 + tx;
    if (r < nrows) {
        #pragma unroll
        for (int i = 0; i < 32; i += 8)
            dst[(size_t)(c0 + ty + i) * nrows + r] = tile[tx][ty + i];
    }
}

// =====================================================================
// g spectrum (one head) — unchanged fp32
// =====================================================================
__global__ __launch_bounds__(512) void gfft_k(
    const float* __restrict__ gcm, const float* __restrict__ RTc,
    const float* __restrict__ Mg, float* __restrict__ Ghat)
{
    __shared__ float Gs[GROWS];
    __shared__ float Tg[222 * 17];
    int tid = threadIdx.x, d = blockIdx.x, kq0 = blockIdx.y * 17;
    int C = min(17, 65 - kq0), C2 = 2 * C;
    const float* src = gcm + (size_t)d * GROWS;
    for (int i = tid; i < GROWS; i += 512) Gs[i] = src[i];
    float* gout = Ghat + (size_t)d * FREQ;
    __syncthreads();
    for (int o = tid; o < 111 * C2; o += 512) {
        int p = o / C2, cc = o % C2;
        int col = (cc < C) ? (kq0 + cc) : (65 + kq0 + (cc - C));
        const float* gp = Gs + p * 111;
        const float* rp = RTc + col;
        float acc = 0.f;
        #pragma unroll 8
        for (int q = 0; q < 111; ++q) acc = fmaf(gp[q], rp[q * 130], acc);
        Tg[p * C2 + cc] = acc;
    }
    __syncthreads();
    for (int o = tid; o < 128 * C; o += 512) {
        int r = o / C, c = o % C;
        const float* m1 = Mg + (size_t)r * 222;
        const float* m2 = Mg + (size_t)(r + 128) * 222;
        float a1 = 0.f, a2 = 0.f;
        #pragma unroll 8
        for (int ss = 0; ss < 111; ++ss) {
            float tre = Tg[ss * C2 + c];
            a1 = fmaf(m1[ss], tre, a1); a2 = fmaf(m2[ss], tre, a2);
        }
        #pragma unroll 8
        for (int ss = 0; ss < 111; ++ss) {
            float tim = Tg[ss * C2 + C + c];
            a1 = fmaf(m1[111 + ss], tim, a1); a2 = fmaf(m2[111 + ss], tim, a2);
        }
        gout[r * 65 + kq0 + c] = a1;
        gout[8320 + r * 65 + kq0 + c] = a2;
    }
}

// =====================================================================
// v conv (one head, in-place) — unchanged from R3
// =====================================================================
__global__ __launch_bounds__(512) void vfft_k(
    float* __restrict__ vcm, const float* __restrict__ Ghat,
    const float* __restrict__ RTc136, const float* __restrict__ MvT,
    const float* __restrict__ M2cT, const float* __restrict__ RT2cT)
{
    __shared__ float Vs[POS];
    __shared__ float Tq[112 * 36];
    __shared__ float Vh[256 * 32];
    const int tid = threadIdx.x;
    const int d = blockIdx.x >> 3, b = blockIdx.x & 7;
    float* chan = vcm + (size_t)(b * 128 + d) * POS;
    float ys[7];
    int p5[7], b5[7];
    #pragma unroll
    for (int i = 0; i < 7; ++i) {
        ys[i] = 0.f;
        int o = tid + 512 * i;
        p5[i] = o / 56; b5[i] = o - p5[i] * 56;
    }
    for (int i = tid; i < POS; i += 512) Vs[i] = chan[i];
    const float* gre = Ghat + (size_t)d * FREQ;

    for (int ck = 0; ck < 2; ++ck) {
        const int kq0 = ck * 32;
        __syncthreads();
        if (tid < 448) {    // S1
            const int region = tid & 1;
            const int t2 = tid >> 1;
            const int p0 = (t2 >> 3) << 1;
            const int c0 = (t2 & 7) << 2;
            const float* rbase = RTc136 + (region ? 68 : 0) + kq0 + c0;
            const float* v0 = Vs + p0 * 56;
            const float* v1 = v0 + 56;
            float a0x=0,a0y=0,a0z=0,a0w=0, a1x=0,a1y=0,a1z=0,a1w=0;
            for (int q = 0; q < 56; ++q) {
                float4 rv = *(const float4*)(rbase + q * 136);
                float x0 = v0[q], x1 = v1[q];
                a0x = fmaf(x0, rv.x, a0x); a0y = fmaf(x0, rv.y, a0y);
                a0z = fmaf(x0, rv.z, a0z); a0w = fmaf(x0, rv.w, a0w);
                a1x = fmaf(x1, rv.x, a1x); a1y = fmaf(x1, rv.y, a1y);
                a1z = fmaf(x1, rv.z, a1z); a1w = fmaf(x1, rv.w, a1w);
            }
            const int pr = region * 56 + p0;
            *(float4*)&Tq[pr * 36 + c0]       = make_float4(a0x, a0y, a0z, a0w);
            *(float4*)&Tq[(pr + 1) * 36 + c0] = make_float4(a1x, a1y, a1z, a1w);
        }
        __syncthreads();
        {                   // S2
            const int r0 = (tid >> 3) << 2;
            const int c0 = (tid & 7) << 2;
            float acc[4][4] = {};
            for (int s = 0; s < 112; ++s) {
                float4 m = *(const float4*)(MvT + s * 256 + r0);
                float4 tt = *(const float4*)&Tq[s * 36 + c0];
                acc[0][0]=fmaf(m.x,tt.x,acc[0][0]); acc[0][1]=fmaf(m.x,tt.y,acc[0][1]);
                acc[0][2]=fmaf(m.x,tt.z,acc[0][2]); acc[0][3]=fmaf(m.x,tt.w,acc[0][3]);
                acc[1][0]=fmaf(m.y,tt.x,acc[1][0]); acc[1][1]=fmaf(m.y,tt.y,acc[1][1]);
                acc[1][2]=fmaf(m.y,tt.z,acc[1][2]); acc[1][3]=fmaf(m.y,tt.w,acc[1][3]);
                acc[2][0]=fmaf(m.z,tt.x,acc[2][0]); acc[2][1]=fmaf(m.z,tt.y,acc[2][1]);
                acc[2][2]=fmaf(m.z,tt.z,acc[2][2]); acc[2][3]=fmaf(m.z,tt.w,acc[2][3]);
                acc[3][0]=fmaf(m.w,tt.x,acc[3][0]); acc[3][1]=fmaf(m.w,tt.y,acc[3][1]);
                acc[3][2]=fmaf(m.w,tt.z,acc[3][2]); acc[3][3]=fmaf(m.w,tt.w,acc[3][3]);
            }
            #pragma unroll
            for (int i = 0; i < 4; ++i)
                *(float4*)&Vh[(r0 + i) * 32 + c0] =
                    make_float4(acc[i][0], acc[i][1], acc[i][2], acc[i][3]);
        }
        __syncthreads();
        #pragma unroll
        for (int i = 0; i < 8; ++i) {   // S3
            int o = tid + 512 * i;
            int kp = o >> 5, c = o & 31;
            float vr = Vh[kp * 32 + c], vi = Vh[(128 + kp) * 32 + c];
            int gi_ = kp * 65 + kq0 + c;
            float gr = gre[gi_], gm = gre[8320 + gi_];
            Vh[kp * 32 + c] = vr * gr - vi * gm;
            Vh[(128 + kp) * 32 + c] = vr * gm + vi * gr;
        }
        __syncthreads();
        if (tid < 448) {    // S4
            const int r0 = (tid >> 3) << 1;
            const int c0 = (tid & 7) << 2;
            float acc[2][4] = {};
            for (int s = 0; s < 256; ++s) {
                float2 m = *(const float2*)(M2cT + s * 112 + r0);
                float4 v = *(const float4*)&Vh[s * 32 + c0];
                acc[0][0]=fmaf(m.x,v.x,acc[0][0]); acc[0][1]=fmaf(m.x,v.y,acc[0][1]);
                acc[0][2]=fmaf(m.x,v.z,acc[0][2]); acc[0][3]=fmaf(m.x,v.w,acc[0][3]);
                acc[1][0]=fmaf(m.y,v.x,acc[1][0]); acc[1][1]=fmaf(m.y,v.y,acc[1][1]);
                acc[1][2]=fmaf(m.y,v.z,acc[1][2]); acc[1][3]=fmaf(m.y,v.w,acc[1][3]);
            }
            *(float4*)&Tq[r0 * 36 + c0]       = make_float4(acc[0][0],acc[0][1],acc[0][2],acc[0][3]);
            *(float4*)&Tq[(r0 + 1) * 36 + c0] = make_float4(acc[1][0],acc[1][1],acc[1][2],acc[1][3]);
        }
        __syncthreads();
        #pragma unroll
        for (int i = 0; i < 7; ++i) {   // S5
            if (i < 6 || tid < 64) {
                const float* rt = RT2cT + b5[i] * 136 + kq0;
                const float* q1 = Tq + p5[i] * 36;
                const float* q2 = Tq + (56 + p5[i]) * 36;
                float acc = ys[i];
                #pragma unroll
                for (int cq = 0; cq < 8; ++cq) {
                    float4 rr = *(const float4*)(rt + 4 * cq);
                    float4 ri = *(const float4*)(rt + 68 + 4 * cq);
                    float4 qa = *(const float4*)(q1 + 4 * cq);
                    float4 qb = *(const float4*)(q2 + 4 * cq);
                    acc = fmaf(qa.x, rr.x, acc); acc = fmaf(qa.y, rr.y, acc);
                    acc = fmaf(qa.z, rr.z, acc); acc = fmaf(qa.w, rr.w, acc);
                    acc = fmaf(qb.x, ri.x, acc); acc = fmaf(qb.y, ri.y, acc);
                    acc = fmaf(qb.z, ri.z, acc); acc = fmaf(qb.w, ri.w, acc);
                }
                ys[i] = acc;
            }
        }
    }
    __syncthreads();
    if (tid < 56) {
        const float* vp = Vs + tid * 56;
        float acc = 0.f;
        #pragma unroll 4
        for (int q = 0; q < 56; q += 2) acc += vp[q] - vp[q + 1];
        Tq[tid * 36] = acc;
    }
    __syncthreads();
    if (tid < 256) {
        float acc = 0.f;
        for (int s = 0; s < 56; ++s)
            acc = fmaf(MvT[s * 256 + tid], Tq[s * 36], acc);
        Vh[tid * 32] = acc;
    }
    __syncthreads();
    if (tid < 128) {
        float vr = Vh[tid * 32], vi = Vh[(128 + tid) * 32];
        int gi_ = tid * 65 + 64;
        float gr = gre[gi_], gm = gre[8320 + gi_];
        Vh[tid * 32] = vr * gr - vi * gm;
        Vh[(128 + tid) * 32] = vr * gm + vi * gr;
    }
    __syncthreads();
    if (tid < 112) {
        float acc = 0.f;
        for (int s = 0; s < 256; ++s)
            acc = fmaf(M2cT[s * 112 + tid], Vh[s * 32], acc);
        Tq[tid * 36] = acc;
    }
    __syncthreads();
    #pragma unroll
    for (int i = 0; i < 7; ++i) {
        if (i < 6 || tid < 64) {
            float r1 = RT2cT[b5[i] * 136 + 64];
            float r2 = RT2cT[b5[i] * 136 + 132];
            ys[i] = fmaf(Tq[p5[i] * 36], r1, fmaf(Tq[(56 + p5[i]) * 36], r2, ys[i]));
        }
    }
    #pragma unroll
    for (int i = 0; i < 7; ++i)
        if (i < 6 || tid < 64) chan[tid + 512 * i] = ys[i];
}

// =====================================================================
extern "C" void kernel_launch(void* const* d_in, const int* in_sizes, int n_in,
                              void* d_out, int out_size, void* d_ws, size_t ws_size,
                              hipStream_t stream) {
    (void)in_sizes; (void)n_in; (void)out_size;
    const float* x         = (const float*)d_in[0];
    const float* W_u       = (const float*)d_in[1];
    const float* b_u       = (const float*)d_in[2];
    const float* W_v       = (const float*)d_in[3];
    const float* b_v       = (const float*)d_in[4];
    const float* W_o       = (const float*)d_in[5];
    const float* b_o       = (const float*)d_in[6];
    const float* rpe_in_w  = (const float*)d_in[7];
    const float* rpe_in_b  = (const float*)d_in[8];
    const float* rpe_h_w   = (const float*)d_in[9];
    const float* rpe_h_b   = (const float*)d_in[10];
    const float* rpe_out_w = (const float*)d_in[11];
    const float* rpe_out_b = (const float*)d_in[12];
    float* out = (float*)d_out;

    if (ws_size < (size_t)WS_FLOATS * 4) {
        probe_k<<<1, 1, 0, stream>>>(out, 1000.0f + (float)((double)ws_size * 1e-6));
        return;
    }
    float* ws     = (float*)d_ws;
    float* RTc    = ws + OFF_RTC;
    float* MvT    = ws + OFF_MVT;
    float* Mg     = ws + OFF_MG;
    float* M2cT   = ws + OFF_M2T;
    float* RT2cT  = ws + OFF_RT2T;
    float* RTc136 = ws + OFF_RTC136;
    float* ninv   = ws + OFF_NINV;
    float* sinv   = ws + OFF_SINV;
    unsigned short* WB  = (unsigned short*)(ws + OFF_WB);
    unsigned short* wub = WB + WB_WU;
    unsigned short* wvb = WB + WB_WV;
    unsigned short* wob = WB + WB_WO;
    unsigned short* whb = WB + WB_WH;
    unsigned short* wrob= WB + WB_WRO;
    unsigned short* tb16= (unsigned short*)(ws + OFF_TB16);
    float* pool   = ws + OFF_POOL;
    float* vcm    = pool;
    float* g_row  = pool;                  // aliases vcm (dead before v written)
    float* g_cm   = pool + 1577088u;
    float* Ghat   = pool + POOL_GHAT;
    unsigned short* u16 = (unsigned short*)Ghat;  // aliases Ghat (dead after vfft)
    float* tA     = out;                   // rpe fp32 ping-pong in d_out
    float* tBf    = out + 6308352u;

    consts_k<<<562, 256, 0, stream>>>(RTc, MvT, Mg, M2cT, RT2cT, RTc136);

    // weights -> bf16
    convw_k<<<2048, 256, 0, stream>>>(W_u, wub, 524288);
    convw_k<<<2048, 256, 0, stream>>>(W_v, wvb, 524288);
    convw_k<<<2048, 256, 0, stream>>>(W_o, wob, 524288);
    convw_k<<<3072, 256, 0, stream>>>(rpe_h_w, whb, 786432);
    convw_k<<<2048, 256, 0, stream>>>(rpe_out_w, wrob, 524288);

    // ---- RPE MLP hidden ladder (fp32 t in d_out, bf16 MFMA GEMMs) ----
    t0_k<<<24642, 256, 0, stream>>>(rpe_in_w, rpe_in_b, tA);
    norms_k<<<3081, 256, 0, stream>>>(tA, sinv, GROWS);
    mgemm_k<<<dim3(4, 97), 256, 0, stream>>>(tA, whb, 512, nullptr, sinv, 1, 0,
        tBf, rpe_h_b, nullptr, nullptr, 0, 0, GROWS, 512, 512);
    norms_k<<<3081, 256, 0, stream>>>(tBf, sinv, GROWS);
    mgemm_k<<<dim3(4, 97), 256, 0, stream>>>(tBf, whb + 262144, 512, nullptr, sinv, 1, 0,
        tA, rpe_h_b + 512, nullptr, nullptr, 0, 0, GROWS, 512, 512);
    norms_k<<<3081, 256, 0, stream>>>(tA, sinv, GROWS);
    mgemm_k<<<dim3(4, 97), 256, 0, stream>>>(tA, whb + 524288, 512, nullptr, sinv, 1, 0,
        tBf, rpe_h_b + 1024, nullptr, nullptr, 0, 0, GROWS, 512, 512);
    norms_k<<<3081, 256, 0, stream>>>(tBf, sinv, GROWS);
    convt_k<<<24642, 256, 0, stream>>>(tBf, sinv, tb16);

    norms_k<<<6272, 256, 0, stream>>>(x, ninv, ROWS);

    // ---- per-head main path ----
    for (int h = 0; h < 8; ++h) {
        const size_t wo = (size_t)h * 65536;   // h*128*512
        mgemm_k<<<dim3(1, 97), 256, 0, stream>>>(tb16, wrob + wo, 512, nullptr, nullptr, 0, 1,
            g_row, rpe_out_b + h * 128, nullptr, nullptr, 0, 0, GROWS, 128, 512);
        transpose128_k<<<dim3(386, 4), dim3(32, 8), 0, stream>>>(g_row, g_cm, GROWS);
        gfft_k<<<dim3(128, 4), 512, 0, stream>>>(g_cm, RTc, Mg, Ghat);
        mgemm_k<<<dim3(1, 196), 256, 0, stream>>>(x, wvb + wo, 512, nullptr, ninv, 0, 0,
            vcm, b_v + h * 128, nullptr, nullptr, 0, 1, ROWS, 128, 512);
        vfft_k<<<1024, 512, 0, stream>>>(vcm, Ghat, RTc136, MvT, M2cT, RT2cT);
        mgemm_k<<<dim3(1, 196), 256, 0, stream>>>(x, wub + wo, 512, nullptr, ninv, 0, 0,
            u16, b_u + h * 128, nullptr, nullptr, 0, 2, ROWS, 128, 512);
        mgemm_k<<<dim3(4, 196), 256, 0, stream>>>(u16, wob + h * 128, 1024, vcm, nullptr, 0, 2,
            nullptr, b_o, x, out, (h == 0) ? 1 : 0, 3, ROWS, 512, 128);
    }
}

// Round 5
// 4327.048 us; speedup vs baseline: 2.1766x; 1.5432x over previous
//
#include <hip/hip_runtime.h>
#include <math.h>

// ---------------- problem sizes ----------------
#define NB 8
#define NN 56
#define POS 3136             // 56*56
#define ROWS 25088           // 8*3136
#define GR 111               // 2N-1
#define GROWS 12321          // 111*111
#define FREQ 16640           // per-channel spectrum: [kq 65][256] (re 128 | im 128)

// ---------------- workspace layout (float offsets), total 36.5 MB ----------------
#define OFF_MVT    0u         // 112x256 fp32 (tail)
#define OFF_M2T    28672u     // 256x112 fp32 (tail)
#define OFF_RT2T   57344u     // 56x136  fp32 (tail)
#define OFF_RTC    64960u     // 111x130 fp32 (gfft row DFT)  (14430, padded to 14432)
#define OFF_MG     79392u     // 256x222 fp32 (gfft col DFT)
// bf16 hi/lo MFMA constants (sizes in fl = ushort/2)
#define OFF_RTCAH  136224u    // [130][64]  4160
#define OFF_RTCAL  140384u
#define OFF_MVAH   144544u    // [256][128] 16384
#define OFF_MVAL   160928u
#define OFF_M2AH   177312u    // [112][256] 14336
#define OFF_M2AL   191648u
#define OFF_RT2BH  205984u    // [64][144]  4608
#define OFF_RT2BL  210592u
#define OFF_NINV   215200u    // 25088
#define OFF_SINV   240288u    // 12336
#define OFF_WB     252624u    // bf16 weights 2,883,584 us = 1,441,792 fl
#define OFF_TB16   1694416u   // 12321x512 bf16 = 3,154,176 fl
#define OFF_POOL   4848592u   // 4,276,224 fl
#define WS_FLOATS  9124816u   // 36.5 MB
// WB sub-offsets (ushort units)
#define WB_WU  0u
#define WB_WV  524288u
#define WB_WO  1048576u
#define WB_WH  1572864u
#define WB_WRO 2359296u
// pool sub-offsets (fl units):
//   Ghat16 @ +0        (1,064,960 fl as us)   [d 128][kq 65][256] bf16
//   u16    @ +1064960  (1,605,632 fl as us)
//   vcm16  @ +2670592  (1,605,632 fl as us)   v/y bf16 channel-major (in-place)
//   g_row  @ +1064960  fp32 (1,577,088) — dead before u16 written
//   g_cm   @ +2642048  fp32 (1,577,088) — dead before vcm16 written
#define POOL_U16   1064960u
#define POOL_VCM   2670592u
#define POOL_GROW  1064960u
#define POOL_GCM   2642048u

typedef __attribute__((ext_vector_type(8))) short bf8_t;
typedef __attribute__((ext_vector_type(8))) unsigned short us8_t;
typedef __attribute__((ext_vector_type(4))) float f4_t;

__device__ inline float bf2f(unsigned short b) {
    union { unsigned u; float f; } v; v.u = ((unsigned)b) << 16; return v.f;
}
__device__ inline unsigned short f2bf(float f) {
    union { float f; unsigned u; } v; v.f = f;
    unsigned r = v.u + 0x7FFF + ((v.u >> 16) & 1);
    return (unsigned short)(r >> 16);
}

__global__ void probe_k(float* out, float code) { out[0] = code; }

// =====================================================================
// fp32 constants (gfft + vfft Nyquist tail). angle reduced: (a*b) mod 128
// =====================================================================
__global__ void consts_k(float* RTc, float* MvT, float* Mg, float* M2cT, float* RT2cT) {
    int idx = blockIdx.x * 256 + threadIdx.x;
    const float STEP = 0.049087385212340526f; // 2*pi/128
    if (idx < 14430) { // RTc[q*130+col]: gfft row DFT
        int q = idx / 130, col = idx % 130;
        int a = (col < 65) ? col : col - 65;
        float th = (float)((a * q) & 127) * STEP;
        RTc[idx] = (col < 65) ? cosf(th) : -sinf(th);
        return;
    }
    idx -= 14430;
    if (idx < 28672) { // MvT[s*256+r]
        int s = idx / 256, r = idx % 256;
        int kp = (r < 128) ? r : r - 128;
        int sp = (s < 56) ? s : s - 56;
        float th = (float)((kp * sp) & 127) * STEP;
        float cv = cosf(th), sv = sinf(th);
        MvT[idx] = (r < 128) ? ((s < 56) ? cv : sv) : ((s < 56) ? -sv : cv);
        return;
    }
    idx -= 28672;
    if (idx < 56832) { // Mg[r*222+s]: gfft col DFT
        int r = idx / 222, s = idx % 222;
        int kp = (r < 128) ? r : r - 128;
        int sp = (s < 111) ? s : s - 111;
        float th = (float)((kp * sp) & 127) * STEP;
        float cv = cosf(th), sv = sinf(th);
        Mg[idx] = (r < 128) ? ((s < 111) ? cv : sv) : ((s < 111) ? -sv : cv);
        return;
    }
    idx -= 56832;
    if (idx < 28672) { // M2cT[s*112+r]
        int s = idx / 112, r = idx % 112;
        int a = (r < 56) ? (r + 55) : (r - 1);
        int kp = (s < 128) ? s : s - 128;
        float th = (float)((kp * a) & 127) * STEP;
        float cv = cosf(th), sv = sinf(th);
        M2cT[idx] = (r < 56) ? ((s < 128) ? cv : -sv) : ((s < 128) ? sv : cv);
        return;
    }
    idx -= 28672;
    if (idx < 7616) { // RT2cT[b*136+col], w/L^2 folded
        int b = idx / 136, col = idx % 136;
        float val = 0.f;
        if (col < 65 || (col >= 68 && col < 133)) {
            int kq = (col < 65) ? col : col - 68;
            float w = (kq == 0 || kq == 64) ? 1.f : 2.f;
            float th = (float)((kq * (b + 55)) & 127) * STEP;
            val = ((col < 65) ? cosf(th) : -sinf(th)) * w * (1.f / 16384.f);
        }
        RT2cT[idx] = val;
    }
}

// =====================================================================
// bf16 hi/lo MFMA constants (derived from fp32 consts; run after consts_k)
// =====================================================================
__global__ void consts2_k(const float* __restrict__ MvT, const float* __restrict__ M2cT,
                          const float* __restrict__ RT2cT,
                          unsigned short* RTcAh, unsigned short* RTcAl,
                          unsigned short* MvAh, unsigned short* MvAl,
                          unsigned short* M2Ah, unsigned short* M2Al,
                          unsigned short* RT2Bh, unsigned short* RT2Bl) {
    int idx = blockIdx.x * 256 + threadIdx.x;
    const float STEP = 0.049087385212340526f;
    float v = 0.f; unsigned short *ph, *pl; int off;
    if (idx < 8320) {               // RTcA [130 rows (65 re | 65 im)][64]
        int row = idx >> 6, q = idx & 63;
        if (q < 56) {
            int kq = (row < 65) ? row : row - 65;
            float th = (float)((kq * q) & 127) * STEP;
            v = (row < 65) ? cosf(th) : -sinf(th);
        }
        ph = RTcAh; pl = RTcAl; off = idx;
    } else if (idx < 41088) {       // MvA [256][128] (cols 112..127 zero)
        int i = idx - 8320; int r = i >> 7, s = i & 127;
        if (s < 112) v = MvT[s * 256 + r];
        ph = MvAh; pl = MvAl; off = i;
    } else if (idx < 69760) {       // M2A [112][256]
        int i = idx - 41088; int a = i >> 8, r = i & 255;
        v = M2cT[r * 112 + a];
        ph = M2Ah; pl = M2Al; off = i;
    } else if (idx < 78976) {       // RT2B [64][144]: 0..64 re | 72..136 im
        int i = idx - 69760; int bq = i / 144, col = i % 144;
        if (bq < 56) {
            if (col < 65) v = RT2cT[bq * 136 + col];
            else if (col >= 72 && col < 137) v = RT2cT[bq * 136 + 68 + (col - 72)];
        }
        ph = RT2Bh; pl = RT2Bl; off = i;
    } else return;
    unsigned short h = f2bf(v);
    ph[off] = h;
    pl[off] = f2bf(v - bf2f(h));
}

// =====================================================================
// row L2 norms -> inverse simple-rms scale, D=512
// =====================================================================
__global__ void norms_k(const float* __restrict__ X, float* __restrict__ out, int rows) {
    int row = blockIdx.x * 4 + (threadIdx.x >> 6);
    int lane = threadIdx.x & 63;
    if (row >= rows) return;
    const float* p = X + (size_t)row * 512;
    float s = 0.f;
    #pragma unroll
    for (int i = 0; i < 8; ++i) { float v = p[lane + 64 * i]; s += v * v; }
    #pragma unroll
    for (int o = 32; o > 0; o >>= 1) s += __shfl_down(s, o, 64);
    if (lane == 0) out[row] = 1.f / (sqrtf(s) * 0.04419417382415922f + 1e-8f);
}

__global__ void t0_k(const float* __restrict__ w, const float* __restrict__ b, float* __restrict__ out) {
    int idx = blockIdx.x * 256 + threadIdx.x;
    if (idx >= GROWS * 512) return;
    int r = idx >> 9, c = idx & 511;
    int i = r / 111, j = r % 111;
    float dp = (float)(i - 55), dq = (float)(j - 55);
    out[idx] = dp * w[c * 2] + dq * w[c * 2 + 1] + b[c];
}

__global__ void convw_k(const float* __restrict__ src, unsigned short* __restrict__ dst, int n) {
    int i = blockIdx.x * 256 + threadIdx.x;
    if (i < n) dst[i] = f2bf(src[i]);
}
__global__ void convt_k(const float* __restrict__ t, const float* __restrict__ sinv,
                        unsigned short* __restrict__ dst) {
    int i = blockIdx.x * 256 + threadIdx.x;
    if (i >= GROWS * 512) return;
    int r = i >> 9;
    dst[i] = f2bf(fmaxf(t[i], 0.f) * sinv[r]);
}

// =====================================================================
// bf16 MFMA GEMM (verified fragment pattern), epilogue/amode variants
//  amode 0: A fp32 rm -> relu?*scale -> bf16 ; amode 1: A bf16 rm
//  amode 2: A = bf16(u_bf16[r][k] * y_bf16[((r/POS)*128+k)*POS + r%POS])
//  emode 0: fp32 rm +bias ; emode 2: bf16 rm +bias+silu
//  emode 3: out accum (+bias+xres if first) ; emode 4: bf16 cm +bias+silu
// =====================================================================
__global__ __launch_bounds__(256) void mgemm_k(
    const void* __restrict__ Aptr, const unsigned short* __restrict__ B, int ldb,
    const unsigned short* __restrict__ yv, const float* __restrict__ scale,
    int relu_in, int amode,
    void* __restrict__ Cptr, const float* __restrict__ bias,
    const float* __restrict__ xres, float* __restrict__ outAcc, int first,
    int emode, int M, int N, int K)
{
    __shared__ __align__(16) unsigned short As[4096];
    __shared__ __align__(16) unsigned short Bs[4096];
    const int t = threadIdx.x;
    const int lane = t & 63;
    const int quad = lane >> 4, ln = lane & 15;
    const int wave = t >> 6;
    const int wm = (wave >> 1) << 6, wn = (wave & 1) << 6;
    const int row0 = blockIdx.y << 7, col0 = blockIdx.x << 7;
    const int sc = t & 3;
    const int sm = t >> 2;
    const float* Af = (const float*)Aptr;
    const unsigned short* Au = (const unsigned short*)Aptr;
    f4_t acc[4][4];
    #pragma unroll
    for (int i = 0; i < 4; ++i)
        #pragma unroll
        for (int j = 0; j < 4; ++j)
            acc[i][j] = (f4_t){0.f, 0.f, 0.f, 0.f};

    for (int k0 = 0; k0 < K; k0 += 32) {
        #pragma unroll
        for (int rep = 0; rep < 2; ++rep) {
            const int m = sm + (rep << 6);
            const int am = row0 + m;
            us8_t av = {0, 0, 0, 0, 0, 0, 0, 0};
            if (am < M) {
                if (amode == 0) {
                    const float s = scale ? scale[am] : 1.f;
                    const float* ap = Af + (size_t)am * K + k0 + (sc << 3);
                    float4 f1 = *(const float4*)ap;
                    float4 f2 = *(const float4*)(ap + 4);
                    if (relu_in) {
                        f1.x = fmaxf(f1.x, 0.f); f1.y = fmaxf(f1.y, 0.f);
                        f1.z = fmaxf(f1.z, 0.f); f1.w = fmaxf(f1.w, 0.f);
                        f2.x = fmaxf(f2.x, 0.f); f2.y = fmaxf(f2.y, 0.f);
                        f2.z = fmaxf(f2.z, 0.f); f2.w = fmaxf(f2.w, 0.f);
                    }
                    av[0] = f2bf(f1.x * s); av[1] = f2bf(f1.y * s);
                    av[2] = f2bf(f1.z * s); av[3] = f2bf(f1.w * s);
                    av[4] = f2bf(f2.x * s); av[5] = f2bf(f2.y * s);
                    av[6] = f2bf(f2.z * s); av[7] = f2bf(f2.w * s);
                } else if (amode == 1) {
                    av = *(const us8_t*)(Au + (size_t)am * K + k0 + (sc << 3));
                } else {
                    const unsigned short* up = Au + (size_t)am * K + k0 + (sc << 3);
                    const int bb = am / POS, pos = am - bb * POS;
                    const unsigned short* yb = yv + ((size_t)(bb * 128 + k0 + (sc << 3))) * POS + pos;
                    #pragma unroll
                    for (int j = 0; j < 8; ++j)
                        av[j] = f2bf(bf2f(up[j]) * bf2f(yb[(size_t)j * POS]));
                }
            }
            *(us8_t*)&As[(sc << 10) + (m << 3)] = av;
        }
        #pragma unroll
        for (int rep = 0; rep < 2; ++rep) {
            const int n = sm + (rep << 6);
            us8_t bv = *(const us8_t*)(B + (size_t)(col0 + n) * ldb + k0 + (sc << 3));
            *(us8_t*)&Bs[(sc << 10) + (n << 3)] = bv;
        }
        __syncthreads();
        bf8_t af[4], bfr[4];
        #pragma unroll
        for (int i = 0; i < 4; ++i)
            af[i] = *(const bf8_t*)&As[(quad << 10) + ((wm + (i << 4) + ln) << 3)];
        #pragma unroll
        for (int i = 0; i < 4; ++i)
            bfr[i] = *(const bf8_t*)&Bs[(quad << 10) + ((wn + (i << 4) + ln) << 3)];
        #pragma unroll
        for (int i = 0; i < 4; ++i)
            #pragma unroll
            for (int j = 0; j < 4; ++j)
                acc[i][j] = __builtin_amdgcn_mfma_f32_16x16x32_bf16(af[i], bfr[j], acc[i][j], 0, 0, 0);
        __syncthreads();
    }
    #pragma unroll
    for (int i = 0; i < 4; ++i) {
        #pragma unroll
        for (int j = 0; j < 4; ++j) {
            #pragma unroll
            for (int rr = 0; rr < 4; ++rr) {
                const int r = row0 + wm + (i << 4) + (quad << 2) + rr;
                const int c = col0 + wn + (j << 4) + ln;
                if (r >= M) continue;
                float v = acc[i][j][rr];
                if (emode == 0) {
                    v += bias[c];
                    ((float*)Cptr)[(size_t)r * N + c] = v;
                } else if (emode == 2) {
                    v += bias[c]; v = v / (1.f + expf(-v));
                    ((unsigned short*)Cptr)[(size_t)r * N + c] = f2bf(v);
                } else if (emode == 4) {
                    v += bias[c]; v = v / (1.f + expf(-v));
                    const int bb = r / POS, pos = r - bb * POS;
                    ((unsigned short*)Cptr)[((size_t)(bb * 128 + c)) * POS + pos] = f2bf(v);
                } else {
                    const size_t oi = (size_t)r * 512 + c;
                    v += first ? (bias[c] + xres[oi]) : outAcc[oi];
                    outAcc[oi] = v;
                }
            }
        }
    }
}

// =====================================================================
// transpose: src [nrows x 128] fp32 -> dst [128 x nrows]
// =====================================================================
__global__ void transpose128_k(const float* __restrict__ src, float* __restrict__ dst, int nrows) {
    __shared__ float tile[32][33];
    int r0 = blockIdx.x * 32, c0 = blockIdx.y * 32;
    int tx = threadIdx.x, ty = threadIdx.y;
    #pragma unroll
    for (int i = 0; i < 32; i += 8) {
        int r = r0 + ty + i;
        if (r < nrows) tile[ty + i][tx] = src[(size_t)r * 128 + c0 + tx];
    }
    __syncthreads();
    int r = r0 + tx;
    if (r < nrows) {
        #pragma unroll
        for (int i = 0; i < 32; i += 8)
            dst[(size_t)(c0 + ty + i) * nrows + r] = tile[tx][ty + i];
    }
}

// =====================================================================
// g spectrum (one head): fp32 math, bf16 output in [d][kq][256] layout
// =====================================================================
__global__ __launch_bounds__(512) void gfft_k(
    const float* __restrict__ gcm, const float* __restrict__ RTc,
    const float* __restrict__ Mg, unsigned short* __restrict__ Ghat)
{
    __shared__ float Gs[GROWS];
    __shared__ float Tg[222 * 17];
    int tid = threadIdx.x, d = blockIdx.x, kq0 = blockIdx.y * 17;
    int C = min(17, 65 - kq0), C2 = 2 * C;
    const float* src = gcm + (size_t)d * GROWS;
    for (int i = tid; i < GROWS; i += 512) Gs[i] = src[i];
    unsigned short* gout = Ghat + (size_t)d * FREQ;
    __syncthreads();
    for (int o = tid; o < 111 * C2; o += 512) {
        int p = o / C2, cc = o % C2;
        int col = (cc < C) ? (kq0 + cc) : (65 + kq0 + (cc - C));
        const float* gp = Gs + p * 111;
        const float* rp = RTc + col;
        float acc = 0.f;
        #pragma unroll 8
        for (int q = 0; q < 111; ++q) acc = fmaf(gp[q], rp[q * 130], acc);
        Tg[p * C2 + cc] = acc;
    }
    __syncthreads();
    for (int o = tid; o < 128 * C; o += 512) {
        int r = o / C, c = o % C;
        const float* m1 = Mg + (size_t)r * 222;
        const float* m2 = Mg + (size_t)(r + 128) * 222;
        float a1 = 0.f, a2 = 0.f;
        #pragma unroll 8
        for (int ss = 0; ss < 111; ++ss) {
            float tre = Tg[ss * C2 + c];
            a1 = fmaf(m1[ss], tre, a1); a2 = fmaf(m2[ss], tre, a2);
        }
        #pragma unroll 8
        for (int ss = 0; ss < 111; ++ss) {
            float tim = Tg[ss * C2 + C + c];
            a1 = fmaf(m1[111 + ss], tim, a1); a2 = fmaf(m2[111 + ss], tim, a2);
        }
        gout[(kq0 + c) * 256 + r] = f2bf(a1);
        gout[(kq0 + c) * 256 + 128 + r] = f2bf(a2);
    }
}

// =====================================================================
// v conv (one head, in-place bf16): MFMA DFT stages per channel workgroup.
// All operand frags follow the HW-verified pattern: lane l holds
// X[idx=l&15][k=(l>>4)*8+j]; D[m][n]: row = quad*4+reg, col = l&15.
// Constants hi/lo bf16-split (2 MFMAs) to kill systematic quantization.
// LDS strides padded to (4 mod 32) words -> 2-way bank aliasing (free).
// =====================================================================
__global__ __launch_bounds__(512) void vfft_k(
    unsigned short* __restrict__ vcm, const unsigned short* __restrict__ Ghat,
    const unsigned short* __restrict__ RTcAh, const unsigned short* __restrict__ RTcAl,
    const unsigned short* __restrict__ MvAh,  const unsigned short* __restrict__ MvAl,
    const unsigned short* __restrict__ M2Ah,  const unsigned short* __restrict__ M2Al,
    const unsigned short* __restrict__ RT2Bh, const unsigned short* __restrict__ RT2Bl,
    const float* __restrict__ MvT, const float* __restrict__ M2cT,
    const float* __restrict__ RT2cT)
{
    __shared__ __align__(16) unsigned short Vs[64 * 72];    // [p][q] bf16, zero-pad
    __shared__ __align__(16) unsigned short TqT[32 * 136];  // [kqL][s(112)+pad]
    __shared__ __align__(16) unsigned short VhT[32 * 264];  // [kqL][r(256)+pad]
    __shared__ __align__(16) unsigned short QA[64 * 72];    // [p][k(64)+pad]
    __shared__ float tmp[424];                              // Nyquist temps
    const int tid = threadIdx.x;
    const int lane = tid & 63, wave = tid >> 6;
    const int quad = lane >> 4, ln = lane & 15;
    const int d = blockIdx.x >> 3, b = blockIdx.x & 7;
    unsigned short* chan = vcm + (size_t)(b * 128 + d) * POS;
    const unsigned short* ghd = Ghat + (size_t)d * FREQ;

    for (int i = tid; i < 64 * 72; i += 512) { Vs[i] = 0; QA[i] = 0; }
    {   // TqT K-pad cols 112..127 zero (rows 0..31)
        int rr = tid >> 4, cc = 112 + (tid & 15);
        if (tid < 512) TqT[rr * 136 + cc] = 0;
    }
    __syncthreads();
    for (int i = tid; i < POS; i += 512) {
        int p = i / 56, q = i - p * 56;
        Vs[p * 72 + q] = chan[i];
    }
    f4_t acc5[2] = { (f4_t){0,0,0,0}, (f4_t){0,0,0,0} };
    __syncthreads();

    // ===== Nyquist kq=64 tail (fp32 VALU, tiny) =====
    if (tid < 56) {
        const unsigned short* vp = Vs + tid * 72;
        float a = 0.f;
        for (int q = 0; q < 56; q += 2) a += bf2f(vp[q]) - bf2f(vp[q + 1]);
        tmp[tid] = a;
    }
    __syncthreads();
    if (tid < 256) {
        float a = 0.f;
        for (int s = 0; s < 56; ++s) a = fmaf(MvT[s * 256 + tid], tmp[s], a);
        tmp[56 + tid] = a;
    }
    __syncthreads();
    if (tid < 128) {
        float vr = tmp[56 + tid], vi = tmp[184 + tid];
        float gr = bf2f(ghd[64 * 256 + tid]), gm = bf2f(ghd[64 * 256 + 128 + tid]);
        tmp[56 + tid] = vr * gr - vi * gm;
        tmp[184 + tid] = vr * gm + vi * gr;
    }
    __syncthreads();
    if (tid < 112) {
        float a = 0.f;
        for (int r = 0; r < 256; ++r) a = fmaf(M2cT[r * 112 + tid], tmp[56 + r], a);
        tmp[312 + tid] = a;
    }
    __syncthreads();
    #pragma unroll
    for (int ti = 0; ti < 2; ++ti) {
        int t = wave * 2 + ti, mt = t >> 2, nt = t & 3;
        int bq = nt * 16 + ln;
        if (bq < 56) {
            float r1 = RT2cT[bq * 136 + 64], r2 = RT2cT[bq * 136 + 132];
            #pragma unroll
            for (int rr = 0; rr < 4; ++rr) {
                int p = mt * 16 + quad * 4 + rr;
                if (p < 56) acc5[ti][rr] += tmp[312 + p] * r1 + tmp[368 + p] * r2;
            }
        }
    }

    // ===== main chunks kq0 = 0, 32 =====
    for (int ck = 0; ck < 2; ++ck) {
        const int kq0 = ck * 32;
        __syncthreads();
        // ---- S1: D[c'][p] = RTcA[c'][q] . Vs[p][q], K=64 ----
        #pragma unroll
        for (int ti = 0; ti < 2; ++ti) {
            int t = wave * 2 + ti, mt = t >> 2, nt = t & 3;
            int m = mt * 16 + ln;
            int arow = (m >> 5) * 65 + kq0 + (m & 31);
            int pcol = nt * 16 + ln;
            f4_t a = (f4_t){0, 0, 0, 0};
            #pragma unroll
            for (int ks = 0; ks < 2; ++ks) {
                int k0 = ks * 32 + quad * 8;
                bf8_t Ah = *(const bf8_t*)(RTcAh + arow * 64 + k0);
                bf8_t Al = *(const bf8_t*)(RTcAl + arow * 64 + k0);
                bf8_t Bv = *(const bf8_t*)&Vs[pcol * 72 + k0];
                a = __builtin_amdgcn_mfma_f32_16x16x32_bf16(Ah, Bv, a, 0, 0, 0);
                a = __builtin_amdgcn_mfma_f32_16x16x32_bf16(Al, Bv, a, 0, 0, 0);
            }
            if (pcol < 56) {
                #pragma unroll
                for (int rr = 0; rr < 4; ++rr) {
                    int cp = mt * 16 + quad * 4 + rr;
                    TqT[(cp & 31) * 136 + (cp >> 5) * 56 + pcol] = f2bf(a[rr]);
                }
            }
        }
        __syncthreads();
        // ---- S2: D[r][c] = MvA[r][s] . TqT[c][s], K=128 ----
        #pragma unroll
        for (int ti = 0; ti < 4; ++ti) {
            int t = wave * 4 + ti, mt = t >> 1, nt = t & 1;
            int r = mt * 16 + ln, c = nt * 16 + ln;
            f4_t a = (f4_t){0, 0, 0, 0};
            #pragma unroll
            for (int ks = 0; ks < 4; ++ks) {
                int k0 = ks * 32 + quad * 8;
                bf8_t Ah = *(const bf8_t*)(MvAh + r * 128 + k0);
                bf8_t Al = *(const bf8_t*)(MvAl + r * 128 + k0);
                bf8_t Bv = *(const bf8_t*)&TqT[c * 136 + k0];
                a = __builtin_amdgcn_mfma_f32_16x16x32_bf16(Ah, Bv, a, 0, 0, 0);
                a = __builtin_amdgcn_mfma_f32_16x16x32_bf16(Al, Bv, a, 0, 0, 0);
            }
            int r0 = mt * 16 + quad * 4;
            ushort4 st;
            st.x = f2bf(a[0]); st.y = f2bf(a[1]); st.z = f2bf(a[2]); st.w = f2bf(a[3]);
            *(ushort4*)&VhT[c * 264 + r0] = st;
        }
        __syncthreads();
        // ---- S3: complex multiply with Ghat ----
        #pragma unroll
        for (int i = 0; i < 8; ++i) {
            int o = tid + 512 * i;
            int c = o >> 7, kp = o & 127;
            float vr = bf2f(VhT[c * 264 + kp]), vi = bf2f(VhT[c * 264 + 128 + kp]);
            int gi = (kq0 + c) * 256 + kp;
            float gr = bf2f(ghd[gi]), gm = bf2f(ghd[gi + 128]);
            VhT[c * 264 + kp] = f2bf(vr * gr - vi * gm);
            VhT[c * 264 + 128 + kp] = f2bf(vr * gm + vi * gr);
        }
        __syncthreads();
        // ---- S4: D[a][c] = M2A[a][r] . VhT[c][r], K=256 ----
        #pragma unroll
        for (int ti = 0; ti < 2; ++ti) {
            int t = wave * 2 + ti;
            if (t < 14) {
                int mt = t >> 1, nt = t & 1;
                int aa = mt * 16 + ln, c = nt * 16 + ln;
                f4_t a = (f4_t){0, 0, 0, 0};
                #pragma unroll
                for (int ks = 0; ks < 8; ++ks) {
                    int k0 = ks * 32 + quad * 8;
                    bf8_t Ah = *(const bf8_t*)(M2Ah + aa * 256 + k0);
                    bf8_t Al = *(const bf8_t*)(M2Al + aa * 256 + k0);
                    bf8_t Bv = *(const bf8_t*)&VhT[c * 264 + k0];
                    a = __builtin_amdgcn_mfma_f32_16x16x32_bf16(Ah, Bv, a, 0, 0, 0);
                    a = __builtin_amdgcn_mfma_f32_16x16x32_bf16(Al, Bv, a, 0, 0, 0);
                }
                #pragma unroll
                for (int rr = 0; rr < 4; ++rr) {
                    int av_ = mt * 16 + quad * 4 + rr;
                    int p = (av_ < 56) ? av_ : av_ - 56;
                    int reg = (av_ < 56) ? 0 : 32;
                    QA[p * 72 + reg + c] = f2bf(a[rr]);
                }
            }
        }
        __syncthreads();
        // ---- S5: acc[p][bq] += QA[p][k] . RT2B[bq][k], K=64 ----
        #pragma unroll
        for (int ti = 0; ti < 2; ++ti) {
            int t = wave * 2 + ti, mt = t >> 2, nt = t & 3;
            int p = mt * 16 + ln, bq = nt * 16 + ln;
            #pragma unroll
            for (int ks = 0; ks < 2; ++ks) {
                int k0 = ks * 32 + quad * 8;
                bf8_t Aq = *(const bf8_t*)&QA[p * 72 + k0];
                int col = (ks ? 72 : 0) + kq0 + quad * 8;
                bf8_t Bh = *(const bf8_t*)(RT2Bh + bq * 144 + col);
                bf8_t Bl = *(const bf8_t*)(RT2Bl + bq * 144 + col);
                acc5[ti] = __builtin_amdgcn_mfma_f32_16x16x32_bf16(Aq, Bh, acc5[ti], 0, 0, 0);
                acc5[ti] = __builtin_amdgcn_mfma_f32_16x16x32_bf16(Aq, Bl, acc5[ti], 0, 0, 0);
            }
        }
    }
    // ===== store y (bf16, in place) =====
    #pragma unroll
    for (int ti = 0; ti < 2; ++ti) {
        int t = wave * 2 + ti, mt = t >> 2, nt = t & 3;
        int bq = nt * 16 + ln;
        if (bq < 56) {
            #pragma unroll
            for (int rr = 0; rr < 4; ++rr) {
                int p = mt * 16 + quad * 4 + rr;
                if (p < 56) chan[p * 56 + bq] = f2bf(acc5[ti][rr]);
            }
        }
    }
}

// =====================================================================
extern "C" void kernel_launch(void* const* d_in, const int* in_sizes, int n_in,
                              void* d_out, int out_size, void* d_ws, size_t ws_size,
                              hipStream_t stream) {
    (void)in_sizes; (void)n_in; (void)out_size;
    const float* x         = (const float*)d_in[0];
    const float* W_u       = (const float*)d_in[1];
    const float* b_u       = (const float*)d_in[2];
    const float* W_v       = (const float*)d_in[3];
    const float* b_v       = (const float*)d_in[4];
    const float* W_o       = (const float*)d_in[5];
    const float* b_o       = (const float*)d_in[6];
    const float* rpe_in_w  = (const float*)d_in[7];
    const float* rpe_in_b  = (const float*)d_in[8];
    const float* rpe_h_w   = (const float*)d_in[9];
    const float* rpe_h_b   = (const float*)d_in[10];
    const float* rpe_out_w = (const float*)d_in[11];
    const float* rpe_out_b = (const float*)d_in[12];
    float* out = (float*)d_out;

    if (ws_size < (size_t)WS_FLOATS * 4) {
        probe_k<<<1, 1, 0, stream>>>(out, 1000.0f + (float)((double)ws_size * 1e-6));
        return;
    }
    float* ws    = (float*)d_ws;
    float* MvT   = ws + OFF_MVT;
    float* M2cT  = ws + OFF_M2T;
    float* RT2cT = ws + OFF_RT2T;
    float* RTc   = ws + OFF_RTC;
    float* Mg    = ws + OFF_MG;
    unsigned short* RTcAh = (unsigned short*)(ws + OFF_RTCAH);
    unsigned short* RTcAl = (unsigned short*)(ws + OFF_RTCAL);
    unsigned short* MvAh  = (unsigned short*)(ws + OFF_MVAH);
    unsigned short* MvAl  = (unsigned short*)(ws + OFF_MVAL);
    unsigned short* M2Ah  = (unsigned short*)(ws + OFF_M2AH);
    unsigned short* M2Al  = (unsigned short*)(ws + OFF_M2AL);
    unsigned short* RT2Bh = (unsigned short*)(ws + OFF_RT2BH);
    unsigned short* RT2Bl = (unsigned short*)(ws + OFF_RT2BL);
    float* ninv  = ws + OFF_NINV;
    float* sinv  = ws + OFF_SINV;
    unsigned short* WB  = (unsigned short*)(ws + OFF_WB);
    unsigned short* wub = WB + WB_WU;
    unsigned short* wvb = WB + WB_WV;
    unsigned short* wob = WB + WB_WO;
    unsigned short* whb = WB + WB_WH;
    unsigned short* wrob= WB + WB_WRO;
    unsigned short* tb16= (unsigned short*)(ws + OFF_TB16);
    float* pool  = ws + OFF_POOL;
    unsigned short* Ghat16 = (unsigned short*)pool;
    unsigned short* u16    = (unsigned short*)(pool + POOL_U16);
    unsigned short* vcm16  = (unsigned short*)(pool + POOL_VCM);
    float* g_row = pool + POOL_GROW;   // dead before u16 written
    float* g_cm  = pool + POOL_GCM;    // dead before vcm16 written
    float* tA    = out;                // rpe fp32 ping-pong in d_out
    float* tBf   = out + 6308352u;

    consts_k<<<533, 256, 0, stream>>>(RTc, MvT, Mg, M2cT, RT2cT);
    consts2_k<<<309, 256, 0, stream>>>(MvT, M2cT, RT2cT, RTcAh, RTcAl,
                                       MvAh, MvAl, M2Ah, M2Al, RT2Bh, RT2Bl);

    // weights -> bf16
    convw_k<<<2048, 256, 0, stream>>>(W_u, wub, 524288);
    convw_k<<<2048, 256, 0, stream>>>(W_v, wvb, 524288);
    convw_k<<<2048, 256, 0, stream>>>(W_o, wob, 524288);
    convw_k<<<3072, 256, 0, stream>>>(rpe_h_w, whb, 786432);
    convw_k<<<2048, 256, 0, stream>>>(rpe_out_w, wrob, 524288);

    // ---- RPE MLP hidden ladder ----
    t0_k<<<24642, 256, 0, stream>>>(rpe_in_w, rpe_in_b, tA);
    norms_k<<<3081, 256, 0, stream>>>(tA, sinv, GROWS);
    mgemm_k<<<dim3(4, 97), 256, 0, stream>>>(tA, whb, 512, nullptr, sinv, 1, 0,
        tBf, rpe_h_b, nullptr, nullptr, 0, 0, GROWS, 512, 512);
    norms_k<<<3081, 256, 0, stream>>>(tBf, sinv, GROWS);
    mgemm_k<<<dim3(4, 97), 256, 0, stream>>>(tBf, whb + 262144, 512, nullptr, sinv, 1, 0,
        tA, rpe_h_b + 512, nullptr, nullptr, 0, 0, GROWS, 512, 512);
    norms_k<<<3081, 256, 0, stream>>>(tA, sinv, GROWS);
    mgemm_k<<<dim3(4, 97), 256, 0, stream>>>(tA, whb + 524288, 512, nullptr, sinv, 1, 0,
        tBf, rpe_h_b + 1024, nullptr, nullptr, 0, 0, GROWS, 512, 512);
    norms_k<<<3081, 256, 0, stream>>>(tBf, sinv, GROWS);
    convt_k<<<24642, 256, 0, stream>>>(tBf, sinv, tb16);

    norms_k<<<6272, 256, 0, stream>>>(x, ninv, ROWS);

    // ---- per-head main path ----
    for (int h = 0; h < 8; ++h) {
        const size_t wo = (size_t)h * 65536;
        mgemm_k<<<dim3(1, 97), 256, 0, stream>>>(tb16, wrob + wo, 512, nullptr, nullptr, 0, 1,
            g_row, rpe_out_b + h * 128, nullptr, nullptr, 0, 0, GROWS, 128, 512);
        transpose128_k<<<dim3(386, 4), dim3(32, 8), 0, stream>>>(g_row, g_cm, GROWS);
        gfft_k<<<dim3(128, 4), 512, 0, stream>>>(g_cm, RTc, Mg, Ghat16);
        mgemm_k<<<dim3(1, 196), 256, 0, stream>>>(x, wvb + wo, 512, nullptr, ninv, 0, 0,
            vcm16, b_v + h * 128, nullptr, nullptr, 0, 4, ROWS, 128, 512);
        vfft_k<<<1024, 512, 0, stream>>>(vcm16, Ghat16, RTcAh, RTcAl, MvAh, MvAl,
            M2Ah, M2Al, RT2Bh, RT2Bl, MvT, M2cT, RT2cT);
        mgemm_k<<<dim3(1, 196), 256, 0, stream>>>(x, wub + wo, 512, nullptr, ninv, 0, 0,
            u16, b_u + h * 128, nullptr, nullptr, 0, 2, ROWS, 128, 512);
        mgemm_k<<<dim3(4, 196), 256, 0, stream>>>(u16, wob + h * 128, 1024, vcm16, nullptr, 0, 2,
            nullptr, b_o, x, out, (h == 0) ? 1 : 0, 3, ROWS, 512, 128);
    }
}